// Round 3
// baseline (1345.676 us; speedup 1.0000x reference)
//
#include <hip/hip_runtime.h>
#include <cstddef>

#define TPB 256
#define SCAN_T 1024

// ---------------------------------------------------------------------------
// Histogram + degree: count[t]++, degp[t]+=max(w,0), degn[t]+=max(-w,0)
// ---------------------------------------------------------------------------
__global__ void hist_kernel(const int* __restrict__ tgt, const float* __restrict__ ew,
                            int* __restrict__ cnt, float* __restrict__ degp,
                            float* __restrict__ degn, int E) {
    int e = blockIdx.x * blockDim.x + threadIdx.x;
    if (e >= E) return;
    int t = tgt[e];
    float w = ew[e];
    atomicAdd(&cnt[t], 1);
    if (w > 0.0f)      atomicAdd(&degp[t], w);
    else if (w < 0.0f) atomicAdd(&degn[t], -w);
}

// dinv = rsqrt(deg + 1) in place (deg >= 0, so always > 0)
__global__ void dinv_kernel(float* __restrict__ degp, float* __restrict__ degn, int n) {
    int i = blockIdx.x * blockDim.x + threadIdx.x;
    if (i >= n) return;
    degp[i] = rsqrtf(degp[i] + 1.0f);
    degn[i] = rsqrtf(degn[i] + 1.0f);
}

// ---------------------------------------------------------------------------
// Single-block exclusive scan: rowstart[0..n] from cnt[0..n)
// ---------------------------------------------------------------------------
__global__ void scan_kernel(const int* __restrict__ cnt, int* __restrict__ rowstart, int n) {
    __shared__ int sm[SCAN_T];
    __shared__ int carry;
    int tid = threadIdx.x;
    if (tid == 0) carry = 0;
    __syncthreads();
    for (int base = 0; base < n; base += SCAN_T) {
        int i = base + tid;
        int v = (i < n) ? cnt[i] : 0;
        sm[tid] = v;
        __syncthreads();
        for (int off = 1; off < SCAN_T; off <<= 1) {
            int add = (tid >= off) ? sm[tid - off] : 0;
            __syncthreads();
            sm[tid] += add;
            __syncthreads();
        }
        int c = carry;
        if (i < n) rowstart[i] = c + sm[tid] - v;
        __syncthreads();
        if (tid == 0) carry = c + sm[SCAN_T - 1];
        __syncthreads();
    }
    if (tid == 0) rowstart[n] = carry;
}

// ---------------------------------------------------------------------------
// Fill CSR payload: edat[slot] = {(src<<1)|negflag, bitcast(norm)}
// norm carries the sign: w<0 edges store dinvn[s]*w*dinvn[t] (negative),
// so a single accumulator handles pos-add and neg-subtract.
// ---------------------------------------------------------------------------
__global__ void fill_kernel(const int* __restrict__ src, const int* __restrict__ tgt,
                            const float* __restrict__ ew,
                            const float* __restrict__ dinvp, const float* __restrict__ dinvn,
                            const int* __restrict__ rowstart, int* __restrict__ cursor,
                            int2* __restrict__ edat, int E) {
    int e = blockIdx.x * blockDim.x + threadIdx.x;
    if (e >= E) return;
    int t = tgt[e], s = src[e];
    float w = ew[e];
    int pos = atomicAdd(&cursor[t], 1);
    int slot = rowstart[t] + pos;
    float nv; int flag;
    if (w >= 0.0f) { nv = dinvp[s] * w * dinvp[t]; flag = 0; }
    else           { nv = dinvn[s] * w * dinvn[t]; flag = 1; }
    edat[slot] = make_int2((s << 1) | flag, __float_as_int(nv));
}

// ---------------------------------------------------------------------------
// Dual GEMM: hp = x @ Wp^T, hn = x @ Wn^T.  W is [OUTF, IN] row-major.
// One thread per row; x row fully in VGPRs (inner k loop FULLY unrolled so
// SROA promotes xr[] — the unroll-16 version spilled to scratch: 426 MB
// FETCH vs 25.6 MB of x). W loads are wave-uniform -> scalar loads.
// ---------------------------------------------------------------------------
template<int IN, int OUTF>
__global__ __launch_bounds__(256) void dual_gemm_kernel(
        const float* __restrict__ x,
        const float* __restrict__ Wp, const float* __restrict__ Wn,
        float* __restrict__ hp, float* __restrict__ hn, int n) {
    int row = blockIdx.x * blockDim.x + threadIdx.x;
    if (row >= n) return;
    float xr[IN];
    const float4* xp = (const float4*)(x + (size_t)row * IN);
#pragma unroll
    for (int q = 0; q < IN / 4; ++q) {
        float4 v = xp[q];
        xr[4*q+0] = v.x; xr[4*q+1] = v.y; xr[4*q+2] = v.z; xr[4*q+3] = v.w;
    }
    const int c_begin = blockIdx.y * (OUTF / 2);
    for (int cg = 0; cg < OUTF / 8; ++cg) {
        const int c = c_begin + cg * 4;
        const float* __restrict__ wp0 = Wp + (size_t)c * IN;
        const float* __restrict__ wn0 = Wn + (size_t)c * IN;
        float ap0 = 0.f, ap1 = 0.f, ap2 = 0.f, ap3 = 0.f;
        float an0 = 0.f, an1 = 0.f, an2 = 0.f, an3 = 0.f;
#pragma unroll
        for (int k = 0; k < IN; ++k) {
            float xv = xr[k];
            ap0 += xv * wp0[k];
            ap1 += xv * wp0[IN + k];
            ap2 += xv * wp0[2 * IN + k];
            ap3 += xv * wp0[3 * IN + k];
            an0 += xv * wn0[k];
            an1 += xv * wn0[IN + k];
            an2 += xv * wn0[2 * IN + k];
            an3 += xv * wn0[3 * IN + k];
        }
        float4 op = {ap0, ap1, ap2, ap3};
        float4 on = {an0, an1, an2, an3};
        *(float4*)(hp + (size_t)row * OUTF + c) = op;
        *(float4*)(hn + (size_t)row * OUTF + c) = on;
    }
}

// ---------------------------------------------------------------------------
// Gather, F=128: one wave per target node. acc += h[src]*norm over in-edges,
// fused epilogue: relu(acc + hp[t]*dp^2 + bp - hn[t]*dn^2 - bn).
// ---------------------------------------------------------------------------
__global__ __launch_bounds__(256) void gather128_kernel(
        const int* __restrict__ rowstart, const int2* __restrict__ edat,
        const float* __restrict__ hp, const float* __restrict__ hn,
        const float* __restrict__ dinvp, const float* __restrict__ dinvn,
        const float* __restrict__ bp, const float* __restrict__ bn,
        float* __restrict__ out, int n) {
    const int lane = threadIdx.x & 63;
    int t = (blockIdx.x * blockDim.x + threadIdx.x) >> 6;
    if (t >= n) return;
    int beg = rowstart[t], end = rowstart[t + 1];
    float2 acc0 = {0.f, 0.f}, acc1 = {0.f, 0.f};
    int e = beg;
    for (; e + 1 < end; e += 2) {
        int2 d0 = edat[e], d1 = edat[e + 1];
        float nv0 = __int_as_float(d0.y), nv1 = __int_as_float(d1.y);
        const float* h0 = (d0.x & 1) ? hn : hp;
        const float* h1 = (d1.x & 1) ? hn : hp;
        float2 v0 = *(const float2*)(h0 + (((size_t)(d0.x >> 1)) << 7) + 2 * lane);
        float2 v1 = *(const float2*)(h1 + (((size_t)(d1.x >> 1)) << 7) + 2 * lane);
        acc0.x += v0.x * nv0; acc0.y += v0.y * nv0;
        acc1.x += v1.x * nv1; acc1.y += v1.y * nv1;
    }
    if (e < end) {
        int2 d0 = edat[e];
        float nv0 = __int_as_float(d0.y);
        const float* h0 = (d0.x & 1) ? hn : hp;
        float2 v0 = *(const float2*)(h0 + (((size_t)(d0.x >> 1)) << 7) + 2 * lane);
        acc0.x += v0.x * nv0; acc0.y += v0.y * nv0;
    }
    float dp = dinvp[t], dn = dinvn[t];
    float sp = dp * dp, sn = dn * dn;
    size_t base = ((size_t)t << 7) + 2 * lane;
    float2 hpv = *(const float2*)(hp + base);
    float2 hnv = *(const float2*)(hn + base);
    float o0 = acc0.x + acc1.x + hpv.x * sp + bp[2*lane]   - hnv.x * sn - bn[2*lane];
    float o1 = acc0.y + acc1.y + hpv.y * sp + bp[2*lane+1] - hnv.y * sn - bn[2*lane+1];
    float2 r = make_float2(fmaxf(o0, 0.f), fmaxf(o1, 0.f));
    *(float2*)(out + base) = r;
}

// Gather, F=64: one wave per target node, one float per lane.
__global__ __launch_bounds__(256) void gather64_kernel(
        const int* __restrict__ rowstart, const int2* __restrict__ edat,
        const float* __restrict__ hp, const float* __restrict__ hn,
        const float* __restrict__ dinvp, const float* __restrict__ dinvn,
        const float* __restrict__ bp, const float* __restrict__ bn,
        float* __restrict__ out, int n) {
    const int lane = threadIdx.x & 63;
    int t = (blockIdx.x * blockDim.x + threadIdx.x) >> 6;
    if (t >= n) return;
    int beg = rowstart[t], end = rowstart[t + 1];
    float acc0 = 0.f, acc1 = 0.f;
    int e = beg;
    for (; e + 1 < end; e += 2) {
        int2 d0 = edat[e], d1 = edat[e + 1];
        float nv0 = __int_as_float(d0.y), nv1 = __int_as_float(d1.y);
        const float* h0 = (d0.x & 1) ? hn : hp;
        const float* h1 = (d1.x & 1) ? hn : hp;
        float v0 = h0[(((size_t)(d0.x >> 1)) << 6) + lane];
        float v1 = h1[(((size_t)(d1.x >> 1)) << 6) + lane];
        acc0 += v0 * nv0;
        acc1 += v1 * nv1;
    }
    if (e < end) {
        int2 d0 = edat[e];
        float nv0 = __int_as_float(d0.y);
        acc0 += ((d0.x & 1) ? hn : hp)[(((size_t)(d0.x >> 1)) << 6) + lane] * nv0;
    }
    float dp = dinvp[t], dn = dinvn[t];
    size_t base = ((size_t)t << 6) + lane;
    float o = acc0 + acc1 + hp[base] * (dp * dp) + bp[lane] - hn[base] * (dn * dn) - bn[lane];
    out[base] = fmaxf(o, 0.f);
}

// ---------------------------------------------------------------------------
extern "C" void kernel_launch(void* const* d_in, const int* in_sizes, int n_in,
                              void* d_out, int out_size, void* d_ws, size_t ws_size,
                              hipStream_t stream) {
    const float* x   = (const float*)d_in[0];
    const int*   ei  = (const int*)d_in[1];
    const float* ew  = (const float*)d_in[2];
    const float* W1p = (const float*)d_in[3];
    const float* b1p = (const float*)d_in[4];
    const float* W1n = (const float*)d_in[5];
    const float* b1n = (const float*)d_in[6];
    const float* W2p = (const float*)d_in[7];
    const float* b2p = (const float*)d_in[8];
    const float* W2n = (const float*)d_in[9];
    const float* b2n = (const float*)d_in[10];

    const int E = in_sizes[2];
    const int n = in_sizes[0] / 64;  // IN = 64
    const int* src = ei;
    const int* tgt = ei + E;

    // ws layout (floats): degp[n] | degn[n] | hp1[128n] | hn1[128n] | h[128n]
    // layer2: hp2/hn2 overwrite hp1 region; out2 uses hn1 region.
    float* ws   = (float*)d_ws;
    float* degp = ws;
    float* degn = ws + n;
    float* hp1  = ws + 2 * (size_t)n;
    float* hn1  = hp1 + (size_t)n * 128;
    float* h    = hn1 + (size_t)n * 128;
    float* hp2  = hp1;
    float* hn2  = hp1 + (size_t)n * 64;
    float* out2 = hn1;

    // CSR parked in d_out (25.6 MB; CSR needs ~14 MB; d_out written last)
    int*  cnt      = (int*)d_out;
    int*  cursor   = cnt + n;
    int*  rowstart = cnt + 2 * n;          // n+1 entries
    int2* edat     = (int2*)(cnt + 3 * n + 2);  // 8B-aligned (3n+2 even)

    hipMemsetAsync(cnt, 0, 2 * (size_t)n * sizeof(int), stream);      // cnt + cursor
    hipMemsetAsync(degp, 0, 2 * (size_t)n * sizeof(float), stream);   // degp + degn

    const int gridE = (E + TPB - 1) / TPB;
    const int gridN = (n + TPB - 1) / TPB;
    const int gridW = (n * 64 + TPB - 1) / TPB;  // one wave per node

    hist_kernel<<<gridE, TPB, 0, stream>>>(tgt, ew, cnt, degp, degn, E);
    dinv_kernel<<<gridN, TPB, 0, stream>>>(degp, degn, n);
    scan_kernel<<<1, SCAN_T, 0, stream>>>(cnt, rowstart, n);
    fill_kernel<<<gridE, TPB, 0, stream>>>(src, tgt, ew, degp, degn, rowstart, cursor, edat, E);

    // ---- layer 1: IN=64 -> H=128 ----
    {
        dim3 g(gridN, 2);
        dual_gemm_kernel<64, 128><<<g, TPB, 0, stream>>>(x, W1p, W1n, hp1, hn1, n);
    }
    gather128_kernel<<<gridW, TPB, 0, stream>>>(rowstart, edat, hp1, hn1, degp, degn,
                                                b1p, b1n, h, n);

    // ---- layer 2: H=128 -> OUT=64 ----
    {
        dim3 g(gridN, 2);
        dual_gemm_kernel<128, 64><<<g, TPB, 0, stream>>>(h, W2p, W2n, hp2, hn2, n);
    }
    gather64_kernel<<<gridW, TPB, 0, stream>>>(rowstart, edat, hp2, hn2, degp, degn,
                                               b2p, b2n, out2, n);

    hipMemcpyAsync(d_out, out2, (size_t)n * 64 * sizeof(float),
                   hipMemcpyDeviceToDevice, stream);
}

// Round 4
// 842.660 us; speedup vs baseline: 1.5969x; 1.5969x over previous
//
#include <hip/hip_runtime.h>
#include <cstddef>

#define TPB 256
#define SCAN_T 1024

// ---------------------------------------------------------------------------
// Histogram + degree: count[t]++, degp[t]+=max(w,0), degn[t]+=max(-w,0)
// ---------------------------------------------------------------------------
__global__ void hist_kernel(const int* __restrict__ tgt, const float* __restrict__ ew,
                            int* __restrict__ cnt, float* __restrict__ degp,
                            float* __restrict__ degn, int E) {
    int e = blockIdx.x * blockDim.x + threadIdx.x;
    if (e >= E) return;
    int t = tgt[e];
    float w = ew[e];
    atomicAdd(&cnt[t], 1);
    if (w > 0.0f)      atomicAdd(&degp[t], w);
    else if (w < 0.0f) atomicAdd(&degn[t], -w);
}

// dinv = rsqrt(deg + 1) in place (deg >= 0, so always > 0)
__global__ void dinv_kernel(float* __restrict__ degp, float* __restrict__ degn, int n) {
    int i = blockIdx.x * blockDim.x + threadIdx.x;
    if (i >= n) return;
    degp[i] = rsqrtf(degp[i] + 1.0f);
    degn[i] = rsqrtf(degn[i] + 1.0f);
}

// ---------------------------------------------------------------------------
// Single-block exclusive scan: rowstart[0..n] from cnt[0..n)
// ---------------------------------------------------------------------------
__global__ void scan_kernel(const int* __restrict__ cnt, int* __restrict__ rowstart, int n) {
    __shared__ int sm[SCAN_T];
    __shared__ int carry;
    int tid = threadIdx.x;
    if (tid == 0) carry = 0;
    __syncthreads();
    for (int base = 0; base < n; base += SCAN_T) {
        int i = base + tid;
        int v = (i < n) ? cnt[i] : 0;
        sm[tid] = v;
        __syncthreads();
        for (int off = 1; off < SCAN_T; off <<= 1) {
            int add = (tid >= off) ? sm[tid - off] : 0;
            __syncthreads();
            sm[tid] += add;
            __syncthreads();
        }
        int c = carry;
        if (i < n) rowstart[i] = c + sm[tid] - v;
        __syncthreads();
        if (tid == 0) carry = c + sm[SCAN_T - 1];
        __syncthreads();
    }
    if (tid == 0) rowstart[n] = carry;
}

// ---------------------------------------------------------------------------
// Fill CSR payload: edat[slot] = {(src<<1)|negflag, bitcast(norm)}
// norm carries the sign: w<0 edges store dinvn[s]*w*dinvn[t] (negative),
// so a single accumulator handles pos-add and neg-subtract.
// ---------------------------------------------------------------------------
__global__ void fill_kernel(const int* __restrict__ src, const int* __restrict__ tgt,
                            const float* __restrict__ ew,
                            const float* __restrict__ dinvp, const float* __restrict__ dinvn,
                            const int* __restrict__ rowstart, int* __restrict__ cursor,
                            int2* __restrict__ edat, int E) {
    int e = blockIdx.x * blockDim.x + threadIdx.x;
    if (e >= E) return;
    int t = tgt[e], s = src[e];
    float w = ew[e];
    int pos = atomicAdd(&cursor[t], 1);
    int slot = rowstart[t] + pos;
    float nv; int flag;
    if (w >= 0.0f) { nv = dinvp[s] * w * dinvp[t]; flag = 0; }
    else           { nv = dinvn[s] * w * dinvn[t]; flag = 1; }
    edat[slot] = make_int2((s << 1) | flag, __float_as_int(nv));
}

// ---------------------------------------------------------------------------
// Tiled dual GEMM: C = X @ W^T.  X is [n, IN] row-major; W is [OUTF, IN]
// row-major.  BM=64 rows x BN=128 cols x BK=32, 256 threads, 4x8 micro-tile
// (32 accumulators/thread).  A and W staged TRANSPOSED in LDS so the inner
// loop is 3x ds_read_b128 + 32 v_fmac per k.  ~25.6 KB LDS -> ~6 blocks/CU.
// DUAL=false: blockIdx.y selects {Wp->hp, Wn->hn} (OUTF == 128 == BN).
// DUAL=true : one pass, cols [0,OUTF) from Wp -> hp, [OUTF,2*OUTF) from Wn -> hn.
// Round-3 lesson: per-thread xr[IN] register rows -> 256 VGPRs, 10% occupancy.
// ---------------------------------------------------------------------------
template<int IN, int OUTF, bool DUAL>
__global__ __launch_bounds__(256) void gemm_tiled(
        const float* __restrict__ x,
        const float* __restrict__ Wp, const float* __restrict__ Wn,
        float* __restrict__ hp, float* __restrict__ hn, int n) {
    constexpr int BM = 64, BN = 128, BK = 32;
    __shared__ float xT[BK][BM + 4];   // stride 68: float4-aligned rows, 2-way banks (free)
    __shared__ float Ws[BK][BN + 4];   // stride 132

    const int tid = threadIdx.x;
    const int rowbase = blockIdx.x * BM;
    const float* __restrict__ Wsel = DUAL ? nullptr : (blockIdx.y ? Wn : Wp);

    const int r0 = (tid & 15) * 4;     // micro-tile rows
    const int c0 = (tid >> 4) * 8;     // micro-tile cols

    float acc[4][8];
#pragma unroll
    for (int i = 0; i < 4; ++i)
#pragma unroll
        for (int j = 0; j < 8; ++j) acc[i][j] = 0.f;

    for (int k0 = 0; k0 < IN; k0 += BK) {
        // ---- stage X tile transposed: 64 rows x 32 k (2 float4 / thread) ----
#pragma unroll
        for (int i = 0; i < (BM * BK) / (4 * TPB); ++i) {
            int lin = tid + i * TPB;           // float4 index
            int row = lin >> 3;                // BK/4 = 8 float4 per row
            int kq  = lin & 7;
            int grow = rowbase + row;
            if (grow > n - 1) grow = n - 1;    // clamp (dup read, never OOB)
            float4 v = *(const float4*)(x + (size_t)grow * IN + k0 + kq * 4);
            int kk = kq * 4;
            xT[kk + 0][row] = v.x; xT[kk + 1][row] = v.y;
            xT[kk + 2][row] = v.z; xT[kk + 3][row] = v.w;
        }
        // ---- stage W tile transposed: 128 cols x 32 k (4 float4 / thread) ----
#pragma unroll
        for (int i = 0; i < (BN * BK) / (4 * TPB); ++i) {
            int lin = tid + i * TPB;
            int c  = lin >> 3;
            int kq = lin & 7;
            const float* wrow;
            if (DUAL) wrow = (c < OUTF) ? (Wp + (size_t)c * IN) : (Wn + (size_t)(c - OUTF) * IN);
            else      wrow = Wsel + (size_t)c * IN;
            float4 v = *(const float4*)(wrow + k0 + kq * 4);
            int kk = kq * 4;
            Ws[kk + 0][c] = v.x; Ws[kk + 1][c] = v.y;
            Ws[kk + 2][c] = v.z; Ws[kk + 3][c] = v.w;
        }
        __syncthreads();

#pragma unroll
        for (int k = 0; k < BK; ++k) {
            float4 a  = *(const float4*)&xT[k][r0];
            float4 b0 = *(const float4*)&Ws[k][c0];
            float4 b1 = *(const float4*)&Ws[k][c0 + 4];
            const float av[4] = {a.x, a.y, a.z, a.w};
            const float bv[8] = {b0.x, b0.y, b0.z, b0.w, b1.x, b1.y, b1.z, b1.w};
#pragma unroll
            for (int i = 0; i < 4; ++i)
#pragma unroll
                for (int j = 0; j < 8; ++j) acc[i][j] += av[i] * bv[j];
        }
        __syncthreads();
    }

    // ---- epilogue: 4 rows x (2 float4) ----
#pragma unroll
    for (int i = 0; i < 4; ++i) {
        int grow = rowbase + r0 + i;
        if (grow >= n) continue;
        float* dst;
        if (DUAL) dst = (c0 < OUTF) ? (hp + (size_t)grow * OUTF + c0)
                                    : (hn + (size_t)grow * OUTF + (c0 - OUTF));
        else      dst = (blockIdx.y ? hn : hp) + (size_t)grow * OUTF + c0;
        float4 o0 = {acc[i][0], acc[i][1], acc[i][2], acc[i][3]};
        float4 o1 = {acc[i][4], acc[i][5], acc[i][6], acc[i][7]};
        *(float4*)dst = o0;
        *(float4*)(dst + 4) = o1;
    }
}

// ---------------------------------------------------------------------------
// Gather, F=128: one wave per target node. acc += h[src]*norm over in-edges,
// fused epilogue: relu(acc + hp[t]*dp^2 + bp - hn[t]*dn^2 - bn).
// ---------------------------------------------------------------------------
__global__ __launch_bounds__(256) void gather128_kernel(
        const int* __restrict__ rowstart, const int2* __restrict__ edat,
        const float* __restrict__ hp, const float* __restrict__ hn,
        const float* __restrict__ dinvp, const float* __restrict__ dinvn,
        const float* __restrict__ bp, const float* __restrict__ bn,
        float* __restrict__ out, int n) {
    const int lane = threadIdx.x & 63;
    int t = (blockIdx.x * blockDim.x + threadIdx.x) >> 6;
    if (t >= n) return;
    int beg = rowstart[t], end = rowstart[t + 1];
    float2 acc0 = {0.f, 0.f}, acc1 = {0.f, 0.f};
    int e = beg;
    for (; e + 1 < end; e += 2) {
        int2 d0 = edat[e], d1 = edat[e + 1];
        float nv0 = __int_as_float(d0.y), nv1 = __int_as_float(d1.y);
        const float* h0 = (d0.x & 1) ? hn : hp;
        const float* h1 = (d1.x & 1) ? hn : hp;
        float2 v0 = *(const float2*)(h0 + (((size_t)(d0.x >> 1)) << 7) + 2 * lane);
        float2 v1 = *(const float2*)(h1 + (((size_t)(d1.x >> 1)) << 7) + 2 * lane);
        acc0.x += v0.x * nv0; acc0.y += v0.y * nv0;
        acc1.x += v1.x * nv1; acc1.y += v1.y * nv1;
    }
    if (e < end) {
        int2 d0 = edat[e];
        float nv0 = __int_as_float(d0.y);
        const float* h0 = (d0.x & 1) ? hn : hp;
        float2 v0 = *(const float2*)(h0 + (((size_t)(d0.x >> 1)) << 7) + 2 * lane);
        acc0.x += v0.x * nv0; acc0.y += v0.y * nv0;
    }
    float dp = dinvp[t], dn = dinvn[t];
    float sp = dp * dp, sn = dn * dn;
    size_t base = ((size_t)t << 7) + 2 * lane;
    float2 hpv = *(const float2*)(hp + base);
    float2 hnv = *(const float2*)(hn + base);
    float o0 = acc0.x + acc1.x + hpv.x * sp + bp[2*lane]   - hnv.x * sn - bn[2*lane];
    float o1 = acc0.y + acc1.y + hpv.y * sp + bp[2*lane+1] - hnv.y * sn - bn[2*lane+1];
    float2 r = make_float2(fmaxf(o0, 0.f), fmaxf(o1, 0.f));
    *(float2*)(out + base) = r;
}

// Gather, F=64: one wave per target node, one float per lane.
__global__ __launch_bounds__(256) void gather64_kernel(
        const int* __restrict__ rowstart, const int2* __restrict__ edat,
        const float* __restrict__ hp, const float* __restrict__ hn,
        const float* __restrict__ dinvp, const float* __restrict__ dinvn,
        const float* __restrict__ bp, const float* __restrict__ bn,
        float* __restrict__ out, int n) {
    const int lane = threadIdx.x & 63;
    int t = (blockIdx.x * blockDim.x + threadIdx.x) >> 6;
    if (t >= n) return;
    int beg = rowstart[t], end = rowstart[t + 1];
    float acc0 = 0.f, acc1 = 0.f;
    int e = beg;
    for (; e + 1 < end; e += 2) {
        int2 d0 = edat[e], d1 = edat[e + 1];
        float nv0 = __int_as_float(d0.y), nv1 = __int_as_float(d1.y);
        const float* h0 = (d0.x & 1) ? hn : hp;
        const float* h1 = (d1.x & 1) ? hn : hp;
        float v0 = h0[(((size_t)(d0.x >> 1)) << 6) + lane];
        float v1 = h1[(((size_t)(d1.x >> 1)) << 6) + lane];
        acc0 += v0 * nv0;
        acc1 += v1 * nv1;
    }
    if (e < end) {
        int2 d0 = edat[e];
        float nv0 = __int_as_float(d0.y);
        acc0 += ((d0.x & 1) ? hn : hp)[(((size_t)(d0.x >> 1)) << 6) + lane] * nv0;
    }
    float dp = dinvp[t], dn = dinvn[t];
    size_t base = ((size_t)t << 6) + lane;
    float o = acc0 + acc1 + hp[base] * (dp * dp) + bp[lane] - hn[base] * (dn * dn) - bn[lane];
    out[base] = fmaxf(o, 0.f);
}

// ---------------------------------------------------------------------------
extern "C" void kernel_launch(void* const* d_in, const int* in_sizes, int n_in,
                              void* d_out, int out_size, void* d_ws, size_t ws_size,
                              hipStream_t stream) {
    const float* x   = (const float*)d_in[0];
    const int*   ei  = (const int*)d_in[1];
    const float* ew  = (const float*)d_in[2];
    const float* W1p = (const float*)d_in[3];
    const float* b1p = (const float*)d_in[4];
    const float* W1n = (const float*)d_in[5];
    const float* b1n = (const float*)d_in[6];
    const float* W2p = (const float*)d_in[7];
    const float* b2p = (const float*)d_in[8];
    const float* W2n = (const float*)d_in[9];
    const float* b2n = (const float*)d_in[10];

    const int E = in_sizes[2];
    const int n = in_sizes[0] / 64;  // IN = 64
    const int* src = ei;
    const int* tgt = ei + E;

    // ws layout (floats): degp[n] | degn[n] | hp1[128n] | hn1[128n] | h[128n]
    // layer2: hp2/hn2 overwrite hp1 region; out2 uses hn1 region.
    float* ws   = (float*)d_ws;
    float* degp = ws;
    float* degn = ws + n;
    float* hp1  = ws + 2 * (size_t)n;
    float* hn1  = hp1 + (size_t)n * 128;
    float* h    = hn1 + (size_t)n * 128;
    float* hp2  = hp1;
    float* hn2  = hp1 + (size_t)n * 64;
    float* out2 = hn1;

    // CSR parked in d_out (25.6 MB; CSR needs ~14 MB; d_out written last)
    int*  cnt      = (int*)d_out;
    int*  cursor   = cnt + n;
    int*  rowstart = cnt + 2 * n;          // n+1 entries
    int2* edat     = (int2*)(cnt + 3 * n + 2);  // 8B-aligned (3n+2 even)

    hipMemsetAsync(cnt, 0, 2 * (size_t)n * sizeof(int), stream);      // cnt + cursor
    hipMemsetAsync(degp, 0, 2 * (size_t)n * sizeof(float), stream);   // degp + degn

    const int gridE = (E + TPB - 1) / TPB;
    const int gridN = (n + TPB - 1) / TPB;
    const int gridW = (n * 64 + TPB - 1) / TPB;  // one wave per node
    const int gridM = (n + 63) / 64;             // GEMM row tiles

    hist_kernel<<<gridE, TPB, 0, stream>>>(tgt, ew, cnt, degp, degn, E);
    dinv_kernel<<<gridN, TPB, 0, stream>>>(degp, degn, n);
    scan_kernel<<<1, SCAN_T, 0, stream>>>(cnt, rowstart, n);
    fill_kernel<<<gridE, TPB, 0, stream>>>(src, tgt, ew, degp, degn, rowstart, cursor, edat, E);

    // ---- layer 1: IN=64 -> H=128 ----
    gemm_tiled<64, 128, false><<<dim3(gridM, 2), TPB, 0, stream>>>(x, W1p, W1n, hp1, hn1, n);
    gather128_kernel<<<gridW, TPB, 0, stream>>>(rowstart, edat, hp1, hn1, degp, degn,
                                                b1p, b1n, h, n);

    // ---- layer 2: H=128 -> OUT=64 (both matrices in one BN=128 pass) ----
    gemm_tiled<128, 64, true><<<dim3(gridM, 1), TPB, 0, stream>>>(h, W2p, W2n, hp2, hn2, n);
    gather64_kernel<<<gridW, TPB, 0, stream>>>(rowstart, edat, hp2, hn2, degp, degn,
                                               b2p, b2n, out2, n);

    hipMemcpyAsync(d_out, out2, (size_t)n * 64 * sizeof(float),
                   hipMemcpyDeviceToDevice, stream);
}

// Round 5
// 685.129 us; speedup vs baseline: 1.9641x; 1.2299x over previous
//
#include <hip/hip_runtime.h>
#include <cstddef>

#define TPB 256
#define SCHUNK 4096   // elements scanned per block (256 thr x 16)

// ---------------------------------------------------------------------------
// Histogram + degree: count[t]++, degp[t]+=max(w,0), degn[t]+=max(-w,0)
// ---------------------------------------------------------------------------
__global__ void hist_kernel(const int* __restrict__ tgt, const float* __restrict__ ew,
                            int* __restrict__ cnt, float* __restrict__ degp,
                            float* __restrict__ degn, int E) {
    int e = blockIdx.x * blockDim.x + threadIdx.x;
    if (e >= E) return;
    int t = tgt[e];
    float w = ew[e];
    atomicAdd(&cnt[t], 1);
    if (w > 0.0f)      atomicAdd(&degp[t], w);
    else if (w < 0.0f) atomicAdd(&degn[t], -w);
}

// dinv = rsqrt(deg + 1) in place (deg >= 0, so always > 0)
__global__ void dinv_kernel(float* __restrict__ degp, float* __restrict__ degn, int n) {
    int i = blockIdx.x * blockDim.x + threadIdx.x;
    if (i >= n) return;
    degp[i] = rsqrtf(degp[i] + 1.0f);
    degn[i] = rsqrtf(degn[i] + 1.0f);
}

// ---------------------------------------------------------------------------
// Parallel exclusive scan, phase 1: per-chunk sums.
// (Round-4 lesson: the single-block 100K-element scan ran 175 us at 0.18%
//  occupancy — pure serialization.)
// ---------------------------------------------------------------------------
__global__ __launch_bounds__(256) void scan_reduce_kernel(
        const int* __restrict__ cnt, int* __restrict__ blocksum, int n) {
    __shared__ int sm[4];
    const int tid = threadIdx.x;
    const int base = blockIdx.x * SCHUNK;
    int s = 0;
    for (int i = tid; i < SCHUNK; i += 256) {
        int idx = base + i;
        if (idx < n) s += cnt[idx];
    }
#pragma unroll
    for (int off = 32; off; off >>= 1) s += __shfl_down(s, off, 64);
    if ((tid & 63) == 0) sm[tid >> 6] = s;
    __syncthreads();
    if (tid == 0) blocksum[blockIdx.x] = sm[0] + sm[1] + sm[2] + sm[3];
}

// Phase 2: per-chunk exclusive scan + global offset from blocksum prefix.
__global__ __launch_bounds__(256) void scan_final_kernel(
        const int* __restrict__ cnt, const int* __restrict__ blocksum,
        int* __restrict__ rowstart, int n) {
    __shared__ int sm[256];
    const int tid = threadIdx.x;
    const int b = blockIdx.x;
    int goff = 0;
    for (int i = 0; i < b; ++i) goff += blocksum[i];   // <=24 iters, L2-hit
    const int start = b * SCHUNK + tid * 16;
    int items[16];
    int tsum = 0;
#pragma unroll
    for (int i = 0; i < 16; ++i) {
        int idx = start + i;
        int v = (idx < n) ? cnt[idx] : 0;
        items[i] = tsum;          // exclusive within thread
        tsum += v;
    }
    sm[tid] = tsum;
    __syncthreads();
#pragma unroll
    for (int off = 1; off < 256; off <<= 1) {
        int add = (tid >= off) ? sm[tid - off] : 0;
        __syncthreads();
        sm[tid] += add;
        __syncthreads();
    }
    const int texcl = goff + sm[tid] - tsum;
#pragma unroll
    for (int i = 0; i < 16; ++i) {
        int idx = start + i;
        if (idx < n) rowstart[idx] = texcl + items[i];
    }
    if (b == gridDim.x - 1 && tid == 255) rowstart[n] = goff + sm[255];
}

// ---------------------------------------------------------------------------
// Fill CSR payload: edat[slot] = {(src<<1)|negflag, bitcast(norm)}
// norm carries the sign: w<0 edges store dinvn[s]*w*dinvn[t] (negative),
// so a single accumulator handles pos-add and neg-subtract.
// ---------------------------------------------------------------------------
__global__ void fill_kernel(const int* __restrict__ src, const int* __restrict__ tgt,
                            const float* __restrict__ ew,
                            const float* __restrict__ dinvp, const float* __restrict__ dinvn,
                            const int* __restrict__ rowstart, int* __restrict__ cursor,
                            int2* __restrict__ edat, int E) {
    int e = blockIdx.x * blockDim.x + threadIdx.x;
    if (e >= E) return;
    int t = tgt[e], s = src[e];
    float w = ew[e];
    int pos = atomicAdd(&cursor[t], 1);
    int slot = rowstart[t] + pos;
    float nv; int flag;
    if (w >= 0.0f) { nv = dinvp[s] * w * dinvp[t]; flag = 0; }
    else           { nv = dinvn[s] * w * dinvn[t]; flag = 1; }
    edat[slot] = make_int2((s << 1) | flag, __float_as_int(nv));
}

// ---------------------------------------------------------------------------
// Tiled dual GEMM: C = X @ W^T.  X is [n, IN] row-major; W is [OUTF, IN]
// row-major.  BM=64 x BN=128 x BK=32, 256 threads, 4x8 micro-tile.
// DUAL=false: blockIdx.y selects {Wp->hp, Wn->hn}.
// DUAL=true : cols [0,OUTF) from Wp -> hp, [OUTF,2*OUTF) from Wn -> hn.
// ---------------------------------------------------------------------------
template<int IN, int OUTF, bool DUAL>
__global__ __launch_bounds__(256) void gemm_tiled(
        const float* __restrict__ x,
        const float* __restrict__ Wp, const float* __restrict__ Wn,
        float* __restrict__ hp, float* __restrict__ hn, int n) {
    constexpr int BM = 64, BN = 128, BK = 32;
    __shared__ float xT[BK][BM + 4];
    __shared__ float Ws[BK][BN + 4];

    const int tid = threadIdx.x;
    const int rowbase = blockIdx.x * BM;
    const float* __restrict__ Wsel = DUAL ? nullptr : (blockIdx.y ? Wn : Wp);

    const int r0 = (tid & 15) * 4;
    const int c0 = (tid >> 4) * 8;

    float acc[4][8];
#pragma unroll
    for (int i = 0; i < 4; ++i)
#pragma unroll
        for (int j = 0; j < 8; ++j) acc[i][j] = 0.f;

    for (int k0 = 0; k0 < IN; k0 += BK) {
#pragma unroll
        for (int i = 0; i < (BM * BK) / (4 * TPB); ++i) {
            int lin = tid + i * TPB;
            int row = lin >> 3;
            int kq  = lin & 7;
            int grow = rowbase + row;
            if (grow > n - 1) grow = n - 1;
            float4 v = *(const float4*)(x + (size_t)grow * IN + k0 + kq * 4);
            int kk = kq * 4;
            xT[kk + 0][row] = v.x; xT[kk + 1][row] = v.y;
            xT[kk + 2][row] = v.z; xT[kk + 3][row] = v.w;
        }
#pragma unroll
        for (int i = 0; i < (BN * BK) / (4 * TPB); ++i) {
            int lin = tid + i * TPB;
            int c  = lin >> 3;
            int kq = lin & 7;
            const float* wrow;
            if (DUAL) wrow = (c < OUTF) ? (Wp + (size_t)c * IN) : (Wn + (size_t)(c - OUTF) * IN);
            else      wrow = Wsel + (size_t)c * IN;
            float4 v = *(const float4*)(wrow + k0 + kq * 4);
            int kk = kq * 4;
            Ws[kk + 0][c] = v.x; Ws[kk + 1][c] = v.y;
            Ws[kk + 2][c] = v.z; Ws[kk + 3][c] = v.w;
        }
        __syncthreads();

#pragma unroll
        for (int k = 0; k < BK; ++k) {
            float4 a  = *(const float4*)&xT[k][r0];
            float4 b0 = *(const float4*)&Ws[k][c0];
            float4 b1 = *(const float4*)&Ws[k][c0 + 4];
            const float av[4] = {a.x, a.y, a.z, a.w};
            const float bv[8] = {b0.x, b0.y, b0.z, b0.w, b1.x, b1.y, b1.z, b1.w};
#pragma unroll
            for (int i = 0; i < 4; ++i)
#pragma unroll
                for (int j = 0; j < 8; ++j) acc[i][j] += av[i] * bv[j];
        }
        __syncthreads();
    }

#pragma unroll
    for (int i = 0; i < 4; ++i) {
        int grow = rowbase + r0 + i;
        if (grow >= n) continue;
        float* dst;
        if (DUAL) dst = (c0 < OUTF) ? (hp + (size_t)grow * OUTF + c0)
                                    : (hn + (size_t)grow * OUTF + (c0 - OUTF));
        else      dst = (blockIdx.y ? hn : hp) + (size_t)grow * OUTF + c0;
        float4 o0 = {acc[i][0], acc[i][1], acc[i][2], acc[i][3]};
        float4 o1 = {acc[i][4], acc[i][5], acc[i][6], acc[i][7]};
        *(float4*)dst = o0;
        *(float4*)(dst + 4) = o1;
    }
}

// ---------------------------------------------------------------------------
// Gather, F=128: one wave per target node. acc += h[src]*norm over in-edges,
// fused epilogue: relu(acc + hp[t]*dp^2 + bp - hn[t]*dn^2 - bn).
// ---------------------------------------------------------------------------
__global__ __launch_bounds__(256) void gather128_kernel(
        const int* __restrict__ rowstart, const int2* __restrict__ edat,
        const float* __restrict__ hp, const float* __restrict__ hn,
        const float* __restrict__ dinvp, const float* __restrict__ dinvn,
        const float* __restrict__ bp, const float* __restrict__ bn,
        float* __restrict__ out, int n) {
    const int lane = threadIdx.x & 63;
    int t = (blockIdx.x * blockDim.x + threadIdx.x) >> 6;
    if (t >= n) return;
    int beg = rowstart[t], end = rowstart[t + 1];
    float2 acc0 = {0.f, 0.f}, acc1 = {0.f, 0.f};
    int e = beg;
    for (; e + 1 < end; e += 2) {
        int2 d0 = edat[e], d1 = edat[e + 1];
        float nv0 = __int_as_float(d0.y), nv1 = __int_as_float(d1.y);
        const float* h0 = (d0.x & 1) ? hn : hp;
        const float* h1 = (d1.x & 1) ? hn : hp;
        float2 v0 = *(const float2*)(h0 + (((size_t)(d0.x >> 1)) << 7) + 2 * lane);
        float2 v1 = *(const float2*)(h1 + (((size_t)(d1.x >> 1)) << 7) + 2 * lane);
        acc0.x += v0.x * nv0; acc0.y += v0.y * nv0;
        acc1.x += v1.x * nv1; acc1.y += v1.y * nv1;
    }
    if (e < end) {
        int2 d0 = edat[e];
        float nv0 = __int_as_float(d0.y);
        const float* h0 = (d0.x & 1) ? hn : hp;
        float2 v0 = *(const float2*)(h0 + (((size_t)(d0.x >> 1)) << 7) + 2 * lane);
        acc0.x += v0.x * nv0; acc0.y += v0.y * nv0;
    }
    float dp = dinvp[t], dn = dinvn[t];
    float sp = dp * dp, sn = dn * dn;
    size_t base = ((size_t)t << 7) + 2 * lane;
    float2 hpv = *(const float2*)(hp + base);
    float2 hnv = *(const float2*)(hn + base);
    float o0 = acc0.x + acc1.x + hpv.x * sp + bp[2*lane]   - hnv.x * sn - bn[2*lane];
    float o1 = acc0.y + acc1.y + hpv.y * sp + bp[2*lane+1] - hnv.y * sn - bn[2*lane+1];
    float2 r = make_float2(fmaxf(o0, 0.f), fmaxf(o1, 0.f));
    *(float2*)(out + base) = r;
}

// Gather, F=64: one wave per target node, one float per lane.
__global__ __launch_bounds__(256) void gather64_kernel(
        const int* __restrict__ rowstart, const int2* __restrict__ edat,
        const float* __restrict__ hp, const float* __restrict__ hn,
        const float* __restrict__ dinvp, const float* __restrict__ dinvn,
        const float* __restrict__ bp, const float* __restrict__ bn,
        float* __restrict__ out, int n) {
    const int lane = threadIdx.x & 63;
    int t = (blockIdx.x * blockDim.x + threadIdx.x) >> 6;
    if (t >= n) return;
    int beg = rowstart[t], end = rowstart[t + 1];
    float acc0 = 0.f, acc1 = 0.f;
    int e = beg;
    for (; e + 1 < end; e += 2) {
        int2 d0 = edat[e], d1 = edat[e + 1];
        float nv0 = __int_as_float(d0.y), nv1 = __int_as_float(d1.y);
        const float* h0 = (d0.x & 1) ? hn : hp;
        const float* h1 = (d1.x & 1) ? hn : hp;
        float v0 = h0[(((size_t)(d0.x >> 1)) << 6) + lane];
        float v1 = h1[(((size_t)(d1.x >> 1)) << 6) + lane];
        acc0 += v0 * nv0;
        acc1 += v1 * nv1;
    }
    if (e < end) {
        int2 d0 = edat[e];
        float nv0 = __int_as_float(d0.y);
        acc0 += ((d0.x & 1) ? hn : hp)[(((size_t)(d0.x >> 1)) << 6) + lane] * nv0;
    }
    float dp = dinvp[t], dn = dinvn[t];
    size_t base = ((size_t)t << 6) + lane;
    float o = acc0 + acc1 + hp[base] * (dp * dp) + bp[lane] - hn[base] * (dn * dn) - bn[lane];
    out[base] = fmaxf(o, 0.f);
}

// ---------------------------------------------------------------------------
extern "C" void kernel_launch(void* const* d_in, const int* in_sizes, int n_in,
                              void* d_out, int out_size, void* d_ws, size_t ws_size,
                              hipStream_t stream) {
    const float* x   = (const float*)d_in[0];
    const int*   ei  = (const int*)d_in[1];
    const float* ew  = (const float*)d_in[2];
    const float* W1p = (const float*)d_in[3];
    const float* b1p = (const float*)d_in[4];
    const float* W1n = (const float*)d_in[5];
    const float* b1n = (const float*)d_in[6];
    const float* W2p = (const float*)d_in[7];
    const float* b2p = (const float*)d_in[8];
    const float* W2n = (const float*)d_in[9];
    const float* b2n = (const float*)d_in[10];

    const int E = in_sizes[2];
    const int n = in_sizes[0] / 64;  // IN = 64
    const int* src = ei;
    const int* tgt = ei + E;

    // ws layout (floats): degp[n] | degn[n] | blocksum[32] | hp1[128n] |
    // hn1[128n] | h[128n].  layer2: hp2/hn2 reuse hp1; out2 uses hn1.
    float* ws   = (float*)d_ws;
    float* degp = ws;
    float* degn = ws + n;
    int*   blocksum = (int*)(ws + 2 * (size_t)n);
    float* hp1  = ws + 2 * (size_t)n + 32;
    float* hn1  = hp1 + (size_t)n * 128;
    float* h    = hn1 + (size_t)n * 128;
    float* hp2  = hp1;
    float* hn2  = hp1 + (size_t)n * 64;
    float* out2 = hn1;

    // CSR parked in d_out (25.6 MB; CSR needs ~14 MB; d_out written last)
    int*  cnt      = (int*)d_out;
    int*  cursor   = cnt + n;
    int*  rowstart = cnt + 2 * n;          // n+1 entries
    int2* edat     = (int2*)(cnt + 3 * n + 2);  // 8B-aligned

    hipMemsetAsync(cnt, 0, 2 * (size_t)n * sizeof(int), stream);
    hipMemsetAsync(degp, 0, 2 * (size_t)n * sizeof(float), stream);

    const int gridE = (E + TPB - 1) / TPB;
    const int gridN = (n + TPB - 1) / TPB;
    const int gridW = (n * 64 + TPB - 1) / TPB;
    const int gridM = (n + 63) / 64;
    const int gridS = (n + SCHUNK - 1) / SCHUNK;

    hist_kernel<<<gridE, TPB, 0, stream>>>(tgt, ew, cnt, degp, degn, E);
    dinv_kernel<<<gridN, TPB, 0, stream>>>(degp, degn, n);
    scan_reduce_kernel<<<gridS, TPB, 0, stream>>>(cnt, blocksum, n);
    scan_final_kernel<<<gridS, TPB, 0, stream>>>(cnt, blocksum, rowstart, n);
    fill_kernel<<<gridE, TPB, 0, stream>>>(src, tgt, ew, degp, degn, rowstart, cursor, edat, E);

    // ---- layer 1: IN=64 -> H=128 ----
    gemm_tiled<64, 128, false><<<dim3(gridM, 2), TPB, 0, stream>>>(x, W1p, W1n, hp1, hn1, n);
    gather128_kernel<<<gridW, TPB, 0, stream>>>(rowstart, edat, hp1, hn1, degp, degn,
                                                b1p, b1n, h, n);

    // ---- layer 2: H=128 -> OUT=64 (both matrices in one BN=128 pass) ----
    gemm_tiled<128, 64, true><<<dim3(gridM, 1), TPB, 0, stream>>>(h, W2p, W2n, hp2, hn2, n);
    gather64_kernel<<<gridW, TPB, 0, stream>>>(rowstart, edat, hp2, hn2, degp, degn,
                                               b2p, b2n, out2, n);

    hipMemcpyAsync(d_out, out2, (size_t)n * 64 * sizeof(float),
                   hipMemcpyDeviceToDevice, stream);
}

// Round 6
// 618.594 us; speedup vs baseline: 2.1754x; 1.1076x over previous
//
#include <hip/hip_runtime.h>
#include <cstddef>

#define TPB 256
#define SCHUNK 4096   // scan elements per block (256 thr x 16)
#define REPL 8        // histogram/cursor replication factor

// ---------------------------------------------------------------------------
// Histogram (count only), 8x replicated to cut per-line atomic serialization.
// Round-5 lesson: 3.2M atomics into 400 KB = ~256 serialized atomics per
// 64B line -> 22.7 G atomics/s. Replica r = blockIdx.x & 7 (must match fill).
// ---------------------------------------------------------------------------
__global__ void hist_kernel(const int* __restrict__ tgt, int* __restrict__ cntR,
                            int n, int E) {
    int e = blockIdx.x * blockDim.x + threadIdx.x;
    if (e >= E) return;
    int r = blockIdx.x & (REPL - 1);
    atomicAdd(&cntR[r * n + tgt[e]], 1);
}

// ---------------------------------------------------------------------------
// Scan phase 1: per-chunk sums over m = 8n elements, key idx = t*8+r.
// ---------------------------------------------------------------------------
__global__ __launch_bounds__(256) void scan_reduce_kernel(
        const int* __restrict__ cntR, int* __restrict__ blocksum, int n, int m) {
    __shared__ int red[4];
    const int tid = threadIdx.x;
    const int base = blockIdx.x * SCHUNK;
    int s = 0;
    for (int i = tid; i < SCHUNK; i += 256) {
        int idx = base + i;
        if (idx < m) s += cntR[(idx & (REPL - 1)) * n + (idx >> 3)];
    }
#pragma unroll
    for (int off = 32; off; off >>= 1) s += __shfl_down(s, off, 64);
    if ((tid & 63) == 0) red[tid >> 6] = s;
    __syncthreads();
    if (tid == 0) blocksum[blockIdx.x] = red[0] + red[1] + red[2] + red[3];
}

// Scan phase 2: exclusive scan + global offset (parallel blocksum prefix).
__global__ __launch_bounds__(256) void scan_final_kernel(
        const int* __restrict__ cntR, const int* __restrict__ blocksum,
        int* __restrict__ rowstart8, int n, int m) {
    __shared__ int sm[256];
    __shared__ int red[4];
    __shared__ int goff_sm;
    const int tid = threadIdx.x;
    const int b = blockIdx.x;
    // goff = sum(blocksum[0..b)) computed in parallel (gridDim.x <= 256)
    int v = (tid < b) ? blocksum[tid] : 0;
#pragma unroll
    for (int off = 32; off; off >>= 1) v += __shfl_down(v, off, 64);
    if ((tid & 63) == 0) red[tid >> 6] = v;
    __syncthreads();
    if (tid == 0) goff_sm = red[0] + red[1] + red[2] + red[3];
    __syncthreads();
    const int goff = goff_sm;

    const int start = b * SCHUNK + tid * 16;
    int items[16];
    int tsum = 0;
#pragma unroll
    for (int i = 0; i < 16; ++i) {
        int idx = start + i;
        int val = (idx < m) ? cntR[(idx & (REPL - 1)) * n + (idx >> 3)] : 0;
        items[i] = tsum;
        tsum += val;
    }
    sm[tid] = tsum;
    __syncthreads();
#pragma unroll
    for (int off = 1; off < 256; off <<= 1) {
        int add = (tid >= off) ? sm[tid - off] : 0;
        __syncthreads();
        sm[tid] += add;
        __syncthreads();
    }
    const int texcl = goff + sm[tid] - tsum;
#pragma unroll
    for (int i = 0; i < 16; ++i) {
        int idx = start + i;
        if (idx < m) rowstart8[idx] = texcl + items[i];
    }
    if (b == gridDim.x - 1 && tid == 255) rowstart8[m] = goff + sm[255];
}

// ---------------------------------------------------------------------------
// Fill CSR: edat[slot] = {(src<<1)|negflag, bitcast(raw w)}.
// No dinv reads (norm finished in gather); replicated cursor (r matches hist).
// ---------------------------------------------------------------------------
__global__ void fill_kernel(const int* __restrict__ src, const int* __restrict__ tgt,
                            const float* __restrict__ ew,
                            const int* __restrict__ rowstart8, int* __restrict__ cursorR,
                            int2* __restrict__ edat, int n, int E) {
    int e = blockIdx.x * blockDim.x + threadIdx.x;
    if (e >= E) return;
    int r = blockIdx.x & (REPL - 1);
    int t = tgt[e], s = src[e];
    float w = ew[e];
    int pos = atomicAdd(&cursorR[r * n + t], 1);
    int slot = rowstart8[t * 8 + r] + pos;
    int flag = (w < 0.0f) ? 1 : 0;
    edat[slot] = make_int2((s << 1) | flag, __float_as_int(w));
}

// ---------------------------------------------------------------------------
// Degrees + dinv, atomic-free: sequential CSR sweep, one thread per node.
// ---------------------------------------------------------------------------
__global__ void deg_dinv_kernel(const int* __restrict__ rowstart8,
                                const int* __restrict__ edat_i,
                                float* __restrict__ dinvp, float* __restrict__ dinvn, int n) {
    int t = blockIdx.x * blockDim.x + threadIdx.x;
    if (t >= n) return;
    int beg = rowstart8[8 * t], end = rowstart8[8 * t + 8];
    float p = 0.f, q = 0.f;
    for (int e = beg; e < end; ++e) {
        float w = __int_as_float(edat_i[2 * e + 1]);
        p += fmaxf(w, 0.f);
        q += fmaxf(-w, 0.f);
    }
    dinvp[t] = rsqrtf(p + 1.0f);
    dinvn[t] = rsqrtf(q + 1.0f);
}

// ---------------------------------------------------------------------------
// Tiled dual GEMM with dinv-scaled epilogue: hp' = (X@Wp^T)*dinvp[row],
// hn' = (X@Wn^T)*dinvn[row].  BM=64 x BN=128 x BK=32, 4x8 micro-tile.
// ---------------------------------------------------------------------------
template<int IN, int OUTF, bool DUAL>
__global__ __launch_bounds__(256) void gemm_tiled(
        const float* __restrict__ x,
        const float* __restrict__ Wp, const float* __restrict__ Wn,
        const float* __restrict__ dinvp, const float* __restrict__ dinvn,
        float* __restrict__ hp, float* __restrict__ hn, int n) {
    constexpr int BM = 64, BN = 128, BK = 32;
    __shared__ float xT[BK][BM + 4];
    __shared__ float Ws[BK][BN + 4];

    const int tid = threadIdx.x;
    const int rowbase = blockIdx.x * BM;
    const float* __restrict__ Wsel = DUAL ? nullptr : (blockIdx.y ? Wn : Wp);

    const int r0 = (tid & 15) * 4;
    const int c0 = (tid >> 4) * 8;

    float acc[4][8];
#pragma unroll
    for (int i = 0; i < 4; ++i)
#pragma unroll
        for (int j = 0; j < 8; ++j) acc[i][j] = 0.f;

    for (int k0 = 0; k0 < IN; k0 += BK) {
#pragma unroll
        for (int i = 0; i < (BM * BK) / (4 * TPB); ++i) {
            int lin = tid + i * TPB;
            int row = lin >> 3;
            int kq  = lin & 7;
            int grow = rowbase + row;
            if (grow > n - 1) grow = n - 1;
            float4 v = *(const float4*)(x + (size_t)grow * IN + k0 + kq * 4);
            int kk = kq * 4;
            xT[kk + 0][row] = v.x; xT[kk + 1][row] = v.y;
            xT[kk + 2][row] = v.z; xT[kk + 3][row] = v.w;
        }
#pragma unroll
        for (int i = 0; i < (BN * BK) / (4 * TPB); ++i) {
            int lin = tid + i * TPB;
            int c  = lin >> 3;
            int kq = lin & 7;
            const float* wrow;
            if (DUAL) wrow = (c < OUTF) ? (Wp + (size_t)c * IN) : (Wn + (size_t)(c - OUTF) * IN);
            else      wrow = Wsel + (size_t)c * IN;
            float4 v = *(const float4*)(wrow + k0 + kq * 4);
            int kk = kq * 4;
            Ws[kk + 0][c] = v.x; Ws[kk + 1][c] = v.y;
            Ws[kk + 2][c] = v.z; Ws[kk + 3][c] = v.w;
        }
        __syncthreads();

#pragma unroll
        for (int k = 0; k < BK; ++k) {
            float4 a  = *(const float4*)&xT[k][r0];
            float4 b0 = *(const float4*)&Ws[k][c0];
            float4 b1 = *(const float4*)&Ws[k][c0 + 4];
            const float av[4] = {a.x, a.y, a.z, a.w};
            const float bv[8] = {b0.x, b0.y, b0.z, b0.w, b1.x, b1.y, b1.z, b1.w};
#pragma unroll
            for (int i = 0; i < 4; ++i)
#pragma unroll
                for (int j = 0; j < 8; ++j) acc[i][j] += av[i] * bv[j];
        }
        __syncthreads();
    }

#pragma unroll
    for (int i = 0; i < 4; ++i) {
        int grow = rowbase + r0 + i;
        if (grow >= n) continue;
        float* dst;
        float sc;
        if (DUAL) {
            bool isP = (c0 < OUTF);
            dst = isP ? (hp + (size_t)grow * OUTF + c0)
                      : (hn + (size_t)grow * OUTF + (c0 - OUTF));
            sc = isP ? dinvp[grow] : dinvn[grow];
        } else {
            dst = (blockIdx.y ? hn : hp) + (size_t)grow * OUTF + c0;
            sc = blockIdx.y ? dinvn[grow] : dinvp[grow];
        }
        float4 o0 = {acc[i][0] * sc, acc[i][1] * sc, acc[i][2] * sc, acc[i][3] * sc};
        float4 o1 = {acc[i][4] * sc, acc[i][5] * sc, acc[i][6] * sc, acc[i][7] * sc};
        *(float4*)dst = o0;
        *(float4*)(dst + 4) = o1;
    }
}

// ---------------------------------------------------------------------------
// Gather, F=128: one wave per target. norm = w * (flag ? dinvn[t] : dinvp[t])
// (dp/dn loop-invariant per wave). hp'/hn' already carry dinv[s].
// Epilogue: relu(acc + dp*hp'[t] + bp - dn*hn'[t] - bn).
// ---------------------------------------------------------------------------
__global__ __launch_bounds__(256) void gather128_kernel(
        const int* __restrict__ rowstart8, const int2* __restrict__ edat,
        const float* __restrict__ hp, const float* __restrict__ hn,
        const float* __restrict__ dinvp, const float* __restrict__ dinvn,
        const float* __restrict__ bp, const float* __restrict__ bn,
        float* __restrict__ out, int n) {
    const int lane = threadIdx.x & 63;
    int t = (blockIdx.x * blockDim.x + threadIdx.x) >> 6;
    if (t >= n) return;
    int beg = rowstart8[8 * t], end = rowstart8[8 * t + 8];
    const float dp = dinvp[t], dn = dinvn[t];
    float2 acc0 = {0.f, 0.f}, acc1 = {0.f, 0.f};
    int e = beg;
    for (; e + 1 < end; e += 2) {
        int2 d0 = edat[e], d1 = edat[e + 1];
        float nv0 = __int_as_float(d0.y) * ((d0.x & 1) ? dn : dp);
        float nv1 = __int_as_float(d1.y) * ((d1.x & 1) ? dn : dp);
        const float* h0 = (d0.x & 1) ? hn : hp;
        const float* h1 = (d1.x & 1) ? hn : hp;
        float2 v0 = *(const float2*)(h0 + (((size_t)(d0.x >> 1)) << 7) + 2 * lane);
        float2 v1 = *(const float2*)(h1 + (((size_t)(d1.x >> 1)) << 7) + 2 * lane);
        acc0.x += v0.x * nv0; acc0.y += v0.y * nv0;
        acc1.x += v1.x * nv1; acc1.y += v1.y * nv1;
    }
    if (e < end) {
        int2 d0 = edat[e];
        float nv0 = __int_as_float(d0.y) * ((d0.x & 1) ? dn : dp);
        const float* h0 = (d0.x & 1) ? hn : hp;
        float2 v0 = *(const float2*)(h0 + (((size_t)(d0.x >> 1)) << 7) + 2 * lane);
        acc0.x += v0.x * nv0; acc0.y += v0.y * nv0;
    }
    size_t base = ((size_t)t << 7) + 2 * lane;
    float2 hpv = *(const float2*)(hp + base);
    float2 hnv = *(const float2*)(hn + base);
    float o0 = acc0.x + acc1.x + hpv.x * dp + bp[2*lane]   - hnv.x * dn - bn[2*lane];
    float o1 = acc0.y + acc1.y + hpv.y * dp + bp[2*lane+1] - hnv.y * dn - bn[2*lane+1];
    float2 r = make_float2(fmaxf(o0, 0.f), fmaxf(o1, 0.f));
    *(float2*)(out + base) = r;
}

// Gather, F=64.
__global__ __launch_bounds__(256) void gather64_kernel(
        const int* __restrict__ rowstart8, const int2* __restrict__ edat,
        const float* __restrict__ hp, const float* __restrict__ hn,
        const float* __restrict__ dinvp, const float* __restrict__ dinvn,
        const float* __restrict__ bp, const float* __restrict__ bn,
        float* __restrict__ out, int n) {
    const int lane = threadIdx.x & 63;
    int t = (blockIdx.x * blockDim.x + threadIdx.x) >> 6;
    if (t >= n) return;
    int beg = rowstart8[8 * t], end = rowstart8[8 * t + 8];
    const float dp = dinvp[t], dn = dinvn[t];
    float acc0 = 0.f, acc1 = 0.f;
    int e = beg;
    for (; e + 1 < end; e += 2) {
        int2 d0 = edat[e], d1 = edat[e + 1];
        float nv0 = __int_as_float(d0.y) * ((d0.x & 1) ? dn : dp);
        float nv1 = __int_as_float(d1.y) * ((d1.x & 1) ? dn : dp);
        const float* h0 = (d0.x & 1) ? hn : hp;
        const float* h1 = (d1.x & 1) ? hn : hp;
        acc0 += h0[(((size_t)(d0.x >> 1)) << 6) + lane] * nv0;
        acc1 += h1[(((size_t)(d1.x >> 1)) << 6) + lane] * nv1;
    }
    if (e < end) {
        int2 d0 = edat[e];
        float nv0 = __int_as_float(d0.y) * ((d0.x & 1) ? dn : dp);
        acc0 += ((d0.x & 1) ? hn : hp)[(((size_t)(d0.x >> 1)) << 6) + lane] * nv0;
    }
    size_t base = ((size_t)t << 6) + lane;
    float o = acc0 + acc1 + hp[base] * dp + bp[lane] - hn[base] * dn - bn[lane];
    out[base] = fmaxf(o, 0.f);
}

// ---------------------------------------------------------------------------
extern "C" void kernel_launch(void* const* d_in, const int* in_sizes, int n_in,
                              void* d_out, int out_size, void* d_ws, size_t ws_size,
                              hipStream_t stream) {
    const float* x   = (const float*)d_in[0];
    const int*   ei  = (const int*)d_in[1];
    const float* ew  = (const float*)d_in[2];
    const float* W1p = (const float*)d_in[3];
    const float* b1p = (const float*)d_in[4];
    const float* W1n = (const float*)d_in[5];
    const float* b1n = (const float*)d_in[6];
    const float* W2p = (const float*)d_in[7];
    const float* b2p = (const float*)d_in[8];
    const float* W2n = (const float*)d_in[9];
    const float* b2n = (const float*)d_in[10];

    const int E = in_sizes[2];
    const int n = in_sizes[0] / 64;  // IN = 64
    const int m = REPL * n;          // scan length
    const int* src = ei;
    const int* tgt = ei + E;

    // ws floats: dinvp[n] | dinvn[n] | blocksum[256] | hp1[128n] | hn1[128n] | h[128n]
    float* ws    = (float*)d_ws;
    float* dinvp = ws;
    float* dinvn = ws + n;
    int*   blocksum = (int*)(ws + 2 * (size_t)n);
    float* hp1   = ws + 2 * (size_t)n + 256;
    float* hn1   = hp1 + (size_t)n * 128;
    float* h     = hn1 + (size_t)n * 128;
    float* hp2   = hp1;
    float* hn2   = hp1 + (size_t)n * 64;
    float* out2  = hn1;

    // d_out ints: cntR[8n] | cursorR[8n] | rowstart8[8n+2] | edat[2E]
    // total = 24n+2+2E = 5.6M+2 ints < 6.4M (d_out floats). Output copied last.
    int*  cntR      = (int*)d_out;
    int*  cursorR   = cntR + m;
    int*  rowstart8 = cntR + 2 * m;
    int2* edat      = (int2*)(cntR + 3 * m + 2);   // even offset -> 8B aligned

    hipMemsetAsync(cntR, 0, 2 * (size_t)m * sizeof(int), stream);  // cntR + cursorR

    const int gridE = (E + TPB - 1) / TPB;
    const int gridN = (n + TPB - 1) / TPB;
    const int gridW = (n * 64 + TPB - 1) / TPB;
    const int gridM = (n + 63) / 64;
    const int gridS = (m + SCHUNK - 1) / SCHUNK;   // 196 <= 256

    hist_kernel<<<gridE, TPB, 0, stream>>>(tgt, cntR, n, E);
    scan_reduce_kernel<<<gridS, TPB, 0, stream>>>(cntR, blocksum, n, m);
    scan_final_kernel<<<gridS, TPB, 0, stream>>>(cntR, blocksum, rowstart8, n, m);
    fill_kernel<<<gridE, TPB, 0, stream>>>(src, tgt, ew, rowstart8, cursorR, edat, n, E);
    deg_dinv_kernel<<<gridN, TPB, 0, stream>>>(rowstart8, (const int*)edat, dinvp, dinvn, n);

    // ---- layer 1: IN=64 -> H=128 ----
    gemm_tiled<64, 128, false><<<dim3(gridM, 2), TPB, 0, stream>>>(
        x, W1p, W1n, dinvp, dinvn, hp1, hn1, n);
    gather128_kernel<<<gridW, TPB, 0, stream>>>(rowstart8, edat, hp1, hn1, dinvp, dinvn,
                                                b1p, b1n, h, n);

    // ---- layer 2: H=128 -> OUT=64 (both matrices in one BN=128 pass) ----
    gemm_tiled<128, 64, true><<<dim3(gridM, 1), TPB, 0, stream>>>(
        h, W2p, W2n, dinvp, dinvn, hp2, hn2, n);
    gather64_kernel<<<gridW, TPB, 0, stream>>>(rowstart8, edat, hp2, hn2, dinvp, dinvn,
                                               b2p, b2n, out2, n);

    hipMemcpyAsync(d_out, out2, (size_t)n * 64 * sizeof(float),
                   hipMemcpyDeviceToDevice, stream);
}

// Round 7
// 571.915 us; speedup vs baseline: 2.3529x; 1.0816x over previous
//
#include <hip/hip_runtime.h>
#include <hip/hip_fp16.h>
#include <cstddef>

#define TPB 256
#define SCHUNK 4096   // scan elements per block (256 thr x 16)
#define REPL 8        // histogram/cursor replication factor

// ---------------------------------------------------------------------------
// Histogram (count only), 8x replicated to cut per-line atomic serialization.
// ---------------------------------------------------------------------------
__global__ void hist_kernel(const int* __restrict__ tgt, int* __restrict__ cntR,
                            int n, int E) {
    int e = blockIdx.x * blockDim.x + threadIdx.x;
    if (e >= E) return;
    int r = blockIdx.x & (REPL - 1);
    atomicAdd(&cntR[r * n + tgt[e]], 1);
}

// ---------------------------------------------------------------------------
// Scan phase 1: per-chunk sums over m = 8n elements, key idx = t*8+r.
// ---------------------------------------------------------------------------
__global__ __launch_bounds__(256) void scan_reduce_kernel(
        const int* __restrict__ cntR, int* __restrict__ blocksum, int n, int m) {
    __shared__ int red[4];
    const int tid = threadIdx.x;
    const int base = blockIdx.x * SCHUNK;
    int s = 0;
    for (int i = tid; i < SCHUNK; i += 256) {
        int idx = base + i;
        if (idx < m) s += cntR[(idx & (REPL - 1)) * n + (idx >> 3)];
    }
#pragma unroll
    for (int off = 32; off; off >>= 1) s += __shfl_down(s, off, 64);
    if ((tid & 63) == 0) red[tid >> 6] = s;
    __syncthreads();
    if (tid == 0) blocksum[blockIdx.x] = red[0] + red[1] + red[2] + red[3];
}

// Scan phase 2: exclusive scan + global offset (parallel blocksum prefix).
__global__ __launch_bounds__(256) void scan_final_kernel(
        const int* __restrict__ cntR, const int* __restrict__ blocksum,
        int* __restrict__ rowstart8, int n, int m) {
    __shared__ int sm[256];
    __shared__ int red[4];
    __shared__ int goff_sm;
    const int tid = threadIdx.x;
    const int b = blockIdx.x;
    int v = (tid < b) ? blocksum[tid] : 0;
#pragma unroll
    for (int off = 32; off; off >>= 1) v += __shfl_down(v, off, 64);
    if ((tid & 63) == 0) red[tid >> 6] = v;
    __syncthreads();
    if (tid == 0) goff_sm = red[0] + red[1] + red[2] + red[3];
    __syncthreads();
    const int goff = goff_sm;

    const int start = b * SCHUNK + tid * 16;
    int items[16];
    int tsum = 0;
#pragma unroll
    for (int i = 0; i < 16; ++i) {
        int idx = start + i;
        int val = (idx < m) ? cntR[(idx & (REPL - 1)) * n + (idx >> 3)] : 0;
        items[i] = tsum;
        tsum += val;
    }
    sm[tid] = tsum;
    __syncthreads();
#pragma unroll
    for (int off = 1; off < 256; off <<= 1) {
        int add = (tid >= off) ? sm[tid - off] : 0;
        __syncthreads();
        sm[tid] += add;
        __syncthreads();
    }
    const int texcl = goff + sm[tid] - tsum;
#pragma unroll
    for (int i = 0; i < 16; ++i) {
        int idx = start + i;
        if (idx < m) rowstart8[idx] = texcl + items[i];
    }
    if (b == gridDim.x - 1 && tid == 255) rowstart8[m] = goff + sm[255];
}

// ---------------------------------------------------------------------------
// Fill CSR: edat[slot] = {(src<<1)|negflag, bitcast(raw w)}.
// ---------------------------------------------------------------------------
__global__ void fill_kernel(const int* __restrict__ src, const int* __restrict__ tgt,
                            const float* __restrict__ ew,
                            const int* __restrict__ rowstart8, int* __restrict__ cursorR,
                            int2* __restrict__ edat, int n, int E) {
    int e = blockIdx.x * blockDim.x + threadIdx.x;
    if (e >= E) return;
    int r = blockIdx.x & (REPL - 1);
    int t = tgt[e], s = src[e];
    float w = ew[e];
    int pos = atomicAdd(&cursorR[r * n + t], 1);
    int slot = rowstart8[t * 8 + r] + pos;
    int flag = (w < 0.0f) ? 1 : 0;
    edat[slot] = make_int2((s << 1) | flag, __float_as_int(w));
}

// ---------------------------------------------------------------------------
// Degrees + dinv, atomic-free CSR sweep, one thread per node.
// ---------------------------------------------------------------------------
__global__ void deg_dinv_kernel(const int* __restrict__ rowstart8,
                                const int* __restrict__ edat_i,
                                float* __restrict__ dinvp, float* __restrict__ dinvn, int n) {
    int t = blockIdx.x * blockDim.x + threadIdx.x;
    if (t >= n) return;
    int beg = rowstart8[8 * t], end = rowstart8[8 * t + 8];
    float p = 0.f, q = 0.f;
    for (int e = beg; e < end; ++e) {
        float w = __int_as_float(edat_i[2 * e + 1]);
        p += fmaxf(w, 0.f);
        q += fmaxf(-w, 0.f);
    }
    dinvp[t] = rsqrtf(p + 1.0f);
    dinvn[t] = rsqrtf(q + 1.0f);
}

// ---------------------------------------------------------------------------
// Tiled dual GEMM, fp32 compute, FP16 OUTPUT with dinv-scaled epilogue:
// hp' = half((X@Wp^T)*dinvp[row]).  Halves gather bytes/edge (Round-6:
// gather FETCH 448 MB at 57% achievable BW was the bottleneck).
// ---------------------------------------------------------------------------
template<int IN, int OUTF, bool DUAL>
__global__ __launch_bounds__(256) void gemm_tiled(
        const float* __restrict__ x,
        const float* __restrict__ Wp, const float* __restrict__ Wn,
        const float* __restrict__ dinvp, const float* __restrict__ dinvn,
        __half* __restrict__ hp, __half* __restrict__ hn, int n) {
    constexpr int BM = 64, BN = 128, BK = 32;
    __shared__ float xT[BK][BM + 4];
    __shared__ float Ws[BK][BN + 4];

    const int tid = threadIdx.x;
    const int rowbase = blockIdx.x * BM;
    const float* __restrict__ Wsel = DUAL ? nullptr : (blockIdx.y ? Wn : Wp);

    const int r0 = (tid & 15) * 4;
    const int c0 = (tid >> 4) * 8;

    float acc[4][8];
#pragma unroll
    for (int i = 0; i < 4; ++i)
#pragma unroll
        for (int j = 0; j < 8; ++j) acc[i][j] = 0.f;

    for (int k0 = 0; k0 < IN; k0 += BK) {
#pragma unroll
        for (int i = 0; i < (BM * BK) / (4 * TPB); ++i) {
            int lin = tid + i * TPB;
            int row = lin >> 3;
            int kq  = lin & 7;
            int grow = rowbase + row;
            if (grow > n - 1) grow = n - 1;
            float4 v = *(const float4*)(x + (size_t)grow * IN + k0 + kq * 4);
            int kk = kq * 4;
            xT[kk + 0][row] = v.x; xT[kk + 1][row] = v.y;
            xT[kk + 2][row] = v.z; xT[kk + 3][row] = v.w;
        }
#pragma unroll
        for (int i = 0; i < (BN * BK) / (4 * TPB); ++i) {
            int lin = tid + i * TPB;
            int c  = lin >> 3;
            int kq = lin & 7;
            const float* wrow;
            if (DUAL) wrow = (c < OUTF) ? (Wp + (size_t)c * IN) : (Wn + (size_t)(c - OUTF) * IN);
            else      wrow = Wsel + (size_t)c * IN;
            float4 v = *(const float4*)(wrow + k0 + kq * 4);
            int kk = kq * 4;
            Ws[kk + 0][c] = v.x; Ws[kk + 1][c] = v.y;
            Ws[kk + 2][c] = v.z; Ws[kk + 3][c] = v.w;
        }
        __syncthreads();

#pragma unroll
        for (int k = 0; k < BK; ++k) {
            float4 a  = *(const float4*)&xT[k][r0];
            float4 b0 = *(const float4*)&Ws[k][c0];
            float4 b1 = *(const float4*)&Ws[k][c0 + 4];
            const float av[4] = {a.x, a.y, a.z, a.w};
            const float bv[8] = {b0.x, b0.y, b0.z, b0.w, b1.x, b1.y, b1.z, b1.w};
#pragma unroll
            for (int i = 0; i < 4; ++i)
#pragma unroll
                for (int j = 0; j < 8; ++j) acc[i][j] += av[i] * bv[j];
        }
        __syncthreads();
    }

#pragma unroll
    for (int i = 0; i < 4; ++i) {
        int grow = rowbase + r0 + i;
        if (grow >= n) continue;
        __half* dst;
        float sc;
        if (DUAL) {
            bool isP = (c0 < OUTF);
            dst = isP ? (hp + (size_t)grow * OUTF + c0)
                      : (hn + (size_t)grow * OUTF + (c0 - OUTF));
            sc = isP ? dinvp[grow] : dinvn[grow];
        } else {
            dst = (blockIdx.y ? hn : hp) + (size_t)grow * OUTF + c0;
            sc = blockIdx.y ? dinvn[grow] : dinvp[grow];
        }
        union { __half2 h2[4]; uint4 u; } pk;
        pk.h2[0] = __floats2half2_rn(acc[i][0] * sc, acc[i][1] * sc);
        pk.h2[1] = __floats2half2_rn(acc[i][2] * sc, acc[i][3] * sc);
        pk.h2[2] = __floats2half2_rn(acc[i][4] * sc, acc[i][5] * sc);
        pk.h2[3] = __floats2half2_rn(acc[i][6] * sc, acc[i][7] * sc);
        *(uint4*)dst = pk.u;
    }
}

// ---------------------------------------------------------------------------
// Gather, F=128, fp16 h rows (fp32 accumulate): one wave per target.
// norm = w * (flag ? dinvn[t] : dinvp[t]).  Output h (fp32) for layer-2 GEMM.
// ---------------------------------------------------------------------------
__global__ __launch_bounds__(256) void gather128_kernel(
        const int* __restrict__ rowstart8, const int2* __restrict__ edat,
        const __half* __restrict__ hp, const __half* __restrict__ hn,
        const float* __restrict__ dinvp, const float* __restrict__ dinvn,
        const float* __restrict__ bp, const float* __restrict__ bn,
        float* __restrict__ out, int n) {
    const int lane = threadIdx.x & 63;
    int t = (blockIdx.x * blockDim.x + threadIdx.x) >> 6;
    if (t >= n) return;
    const __half2* hp2 = (const __half2*)hp;   // row = 64 half2
    const __half2* hn2 = (const __half2*)hn;
    int beg = rowstart8[8 * t], end = rowstart8[8 * t + 8];
    const float dp = dinvp[t], dn = dinvn[t];
    float2 acc0 = {0.f, 0.f}, acc1 = {0.f, 0.f};
    int e = beg;
    for (; e + 1 < end; e += 2) {
        int2 d0 = edat[e], d1 = edat[e + 1];
        float nv0 = __int_as_float(d0.y) * ((d0.x & 1) ? dn : dp);
        float nv1 = __int_as_float(d1.y) * ((d1.x & 1) ? dn : dp);
        const __half2* h0 = (d0.x & 1) ? hn2 : hp2;
        const __half2* h1 = (d1.x & 1) ? hn2 : hp2;
        float2 v0 = __half22float2(h0[((size_t)(d0.x >> 1)) * 64 + lane]);
        float2 v1 = __half22float2(h1[((size_t)(d1.x >> 1)) * 64 + lane]);
        acc0.x += v0.x * nv0; acc0.y += v0.y * nv0;
        acc1.x += v1.x * nv1; acc1.y += v1.y * nv1;
    }
    if (e < end) {
        int2 d0 = edat[e];
        float nv0 = __int_as_float(d0.y) * ((d0.x & 1) ? dn : dp);
        const __half2* h0 = (d0.x & 1) ? hn2 : hp2;
        float2 v0 = __half22float2(h0[((size_t)(d0.x >> 1)) * 64 + lane]);
        acc0.x += v0.x * nv0; acc0.y += v0.y * nv0;
    }
    float2 hpv = __half22float2(hp2[(size_t)t * 64 + lane]);
    float2 hnv = __half22float2(hn2[(size_t)t * 64 + lane]);
    float o0 = acc0.x + acc1.x + hpv.x * dp + bp[2*lane]   - hnv.x * dn - bn[2*lane];
    float o1 = acc0.y + acc1.y + hpv.y * dp + bp[2*lane+1] - hnv.y * dn - bn[2*lane+1];
    float2 r = make_float2(fmaxf(o0, 0.f), fmaxf(o1, 0.f));
    *(float2*)(out + ((size_t)t << 7) + 2 * lane) = r;
}

// Gather, F=64, fp16 h rows: one lane per feature.
__global__ __launch_bounds__(256) void gather64_kernel(
        const int* __restrict__ rowstart8, const int2* __restrict__ edat,
        const __half* __restrict__ hp, const __half* __restrict__ hn,
        const float* __restrict__ dinvp, const float* __restrict__ dinvn,
        const float* __restrict__ bp, const float* __restrict__ bn,
        float* __restrict__ out, int n) {
    const int lane = threadIdx.x & 63;
    int t = (blockIdx.x * blockDim.x + threadIdx.x) >> 6;
    if (t >= n) return;
    int beg = rowstart8[8 * t], end = rowstart8[8 * t + 8];
    const float dp = dinvp[t], dn = dinvn[t];
    float acc0 = 0.f, acc1 = 0.f;
    int e = beg;
    for (; e + 1 < end; e += 2) {
        int2 d0 = edat[e], d1 = edat[e + 1];
        float nv0 = __int_as_float(d0.y) * ((d0.x & 1) ? dn : dp);
        float nv1 = __int_as_float(d1.y) * ((d1.x & 1) ? dn : dp);
        const __half* h0 = (d0.x & 1) ? hn : hp;
        const __half* h1 = (d1.x & 1) ? hn : hp;
        acc0 += __half2float(h0[((size_t)(d0.x >> 1)) * 64 + lane]) * nv0;
        acc1 += __half2float(h1[((size_t)(d1.x >> 1)) * 64 + lane]) * nv1;
    }
    if (e < end) {
        int2 d0 = edat[e];
        float nv0 = __int_as_float(d0.y) * ((d0.x & 1) ? dn : dp);
        acc0 += __half2float(((d0.x & 1) ? hn : hp)[((size_t)(d0.x >> 1)) * 64 + lane]) * nv0;
    }
    float hpv = __half2float(hp[(size_t)t * 64 + lane]);
    float hnv = __half2float(hn[(size_t)t * 64 + lane]);
    float o = acc0 + acc1 + hpv * dp + bp[lane] - hnv * dn - bn[lane];
    out[(size_t)t * 64 + lane] = fmaxf(o, 0.f);
}

// ---------------------------------------------------------------------------
extern "C" void kernel_launch(void* const* d_in, const int* in_sizes, int n_in,
                              void* d_out, int out_size, void* d_ws, size_t ws_size,
                              hipStream_t stream) {
    const float* x   = (const float*)d_in[0];
    const int*   ei  = (const int*)d_in[1];
    const float* ew  = (const float*)d_in[2];
    const float* W1p = (const float*)d_in[3];
    const float* b1p = (const float*)d_in[4];
    const float* W1n = (const float*)d_in[5];
    const float* b1n = (const float*)d_in[6];
    const float* W2p = (const float*)d_in[7];
    const float* b2p = (const float*)d_in[8];
    const float* W2n = (const float*)d_in[9];
    const float* b2n = (const float*)d_in[10];

    const int E = in_sizes[2];
    const int n = in_sizes[0] / 64;  // IN = 64
    const int m = REPL * n;          // scan length
    const int* src = ei;
    const int* tgt = ei + E;

    // ws layout: dinvp[n]f | dinvn[n]f | blocksum[256]i | hp1[128n]h | hn1[128n]h
    //            | h[128n]f.   layer2: hp2/hn2 (64n halves each) reuse hp1;
    //            out2 (64n floats) reuses hn1 (exact byte match: 256n B).
    float*  ws    = (float*)d_ws;
    float*  dinvp = ws;
    float*  dinvn = ws + n;
    int*    blocksum = (int*)(ws + 2 * (size_t)n);
    __half* hp1   = (__half*)(ws + 2 * (size_t)n + 256);
    __half* hn1   = hp1 + (size_t)n * 128;
    float*  h     = (float*)(hn1 + (size_t)n * 128);
    __half* hp2   = hp1;
    __half* hn2   = hp1 + (size_t)n * 64;
    float*  out2  = (float*)hn1;

    // d_out ints: cntR[8n] | cursorR[8n] | rowstart8[8n+2] | edat[2E]
    int*  cntR      = (int*)d_out;
    int*  cursorR   = cntR + m;
    int*  rowstart8 = cntR + 2 * m;
    int2* edat      = (int2*)(cntR + 3 * m + 2);

    hipMemsetAsync(cntR, 0, 2 * (size_t)m * sizeof(int), stream);

    const int gridE = (E + TPB - 1) / TPB;
    const int gridN = (n + TPB - 1) / TPB;
    const int gridW = (n * 64 + TPB - 1) / TPB;
    const int gridM = (n + 63) / 64;
    const int gridS = (m + SCHUNK - 1) / SCHUNK;

    hist_kernel<<<gridE, TPB, 0, stream>>>(tgt, cntR, n, E);
    scan_reduce_kernel<<<gridS, TPB, 0, stream>>>(cntR, blocksum, n, m);
    scan_final_kernel<<<gridS, TPB, 0, stream>>>(cntR, blocksum, rowstart8, n, m);
    fill_kernel<<<gridE, TPB, 0, stream>>>(src, tgt, ew, rowstart8, cursorR, edat, n, E);
    deg_dinv_kernel<<<gridN, TPB, 0, stream>>>(rowstart8, (const int*)edat, dinvp, dinvn, n);

    // ---- layer 1: IN=64 -> H=128 ----
    gemm_tiled<64, 128, false><<<dim3(gridM, 2), TPB, 0, stream>>>(
        x, W1p, W1n, dinvp, dinvn, hp1, hn1, n);
    gather128_kernel<<<gridW, TPB, 0, stream>>>(rowstart8, edat, hp1, hn1, dinvp, dinvn,
                                                b1p, b1n, h, n);

    // ---- layer 2: H=128 -> OUT=64 (both matrices in one BN=128 pass) ----
    gemm_tiled<128, 64, true><<<dim3(gridM, 1), TPB, 0, stream>>>(
        h, W2p, W2n, dinvp, dinvn, hp2, hn2, n);
    gather64_kernel<<<gridW, TPB, 0, stream>>>(rowstart8, edat, hp2, hn2, dinvp, dinvn,
                                               b2p, b2n, out2, n);

    hipMemcpyAsync(d_out, out2, (size_t)n * 64 * sizeof(float),
                   hipMemcpyDeviceToDevice, stream);
}

// Round 8
// 503.218 us; speedup vs baseline: 2.6741x; 1.1365x over previous
//
#include <hip/hip_runtime.h>
#include <hip/hip_fp16.h>
#include <cstddef>

#define TPB 256
#define SCHUNK 4096   // scan elements per block (256 thr x 16)
#define REPL 8        // histogram/cursor replication factor

// ---------------------------------------------------------------------------
// Histogram (count only), 8x replicated to cut per-line atomic serialization.
// ---------------------------------------------------------------------------
__global__ void hist_kernel(const int* __restrict__ tgt, int* __restrict__ cntR,
                            int n, int E) {
    int e = blockIdx.x * blockDim.x + threadIdx.x;
    if (e >= E) return;
    int r = blockIdx.x & (REPL - 1);
    atomicAdd(&cntR[r * n + tgt[e]], 1);
}

// ---------------------------------------------------------------------------
// Scan phase 1: per-chunk sums over m = 8n elements, key idx = t*8+r.
// ---------------------------------------------------------------------------
__global__ __launch_bounds__(256) void scan_reduce_kernel(
        const int* __restrict__ cntR, int* __restrict__ blocksum, int n, int m) {
    __shared__ int red[4];
    const int tid = threadIdx.x;
    const int base = blockIdx.x * SCHUNK;
    int s = 0;
    for (int i = tid; i < SCHUNK; i += 256) {
        int idx = base + i;
        if (idx < m) s += cntR[(idx & (REPL - 1)) * n + (idx >> 3)];
    }
#pragma unroll
    for (int off = 32; off; off >>= 1) s += __shfl_down(s, off, 64);
    if ((tid & 63) == 0) red[tid >> 6] = s;
    __syncthreads();
    if (tid == 0) blocksum[blockIdx.x] = red[0] + red[1] + red[2] + red[3];
}

// Scan phase 2: exclusive scan + global offset (parallel blocksum prefix).
__global__ __launch_bounds__(256) void scan_final_kernel(
        const int* __restrict__ cntR, const int* __restrict__ blocksum,
        int* __restrict__ rowstart8, int n, int m) {
    __shared__ int sm[256];
    __shared__ int red[4];
    __shared__ int goff_sm;
    const int tid = threadIdx.x;
    const int b = blockIdx.x;
    int v = (tid < b) ? blocksum[tid] : 0;
#pragma unroll
    for (int off = 32; off; off >>= 1) v += __shfl_down(v, off, 64);
    if ((tid & 63) == 0) red[tid >> 6] = v;
    __syncthreads();
    if (tid == 0) goff_sm = red[0] + red[1] + red[2] + red[3];
    __syncthreads();
    const int goff = goff_sm;

    const int start = b * SCHUNK + tid * 16;
    int items[16];
    int tsum = 0;
#pragma unroll
    for (int i = 0; i < 16; ++i) {
        int idx = start + i;
        int val = (idx < m) ? cntR[(idx & (REPL - 1)) * n + (idx >> 3)] : 0;
        items[i] = tsum;
        tsum += val;
    }
    sm[tid] = tsum;
    __syncthreads();
#pragma unroll
    for (int off = 1; off < 256; off <<= 1) {
        int add = (tid >= off) ? sm[tid - off] : 0;
        __syncthreads();
        sm[tid] += add;
        __syncthreads();
    }
    const int texcl = goff + sm[tid] - tsum;
#pragma unroll
    for (int i = 0; i < 16; ++i) {
        int idx = start + i;
        if (idx < m) rowstart8[idx] = texcl + items[i];
    }
    if (b == gridDim.x - 1 && tid == 255) rowstart8[m] = goff + sm[255];
}

// ---------------------------------------------------------------------------
// Fill CSR: edat[slot] = {(src<<8)|negflag, bitcast(raw w)}.
// src<<8 IS the byte offset of the fp16 F=128 row (256 B); >>1 for F=64.
// deg_dinv later rewrites .y = norm (layer-independent).
// ---------------------------------------------------------------------------
__global__ void fill_kernel(const int* __restrict__ src, const int* __restrict__ tgt,
                            const float* __restrict__ ew,
                            const int* __restrict__ rowstart8, int* __restrict__ cursorR,
                            int2* __restrict__ edat, int n, int E) {
    int e = blockIdx.x * blockDim.x + threadIdx.x;
    if (e >= E) return;
    int r = blockIdx.x & (REPL - 1);
    int t = tgt[e], s = src[e];
    float w = ew[e];
    int pos = atomicAdd(&cursorR[r * n + t], 1);
    int slot = rowstart8[t * 8 + r] + pos;
    int flag = (w < 0.0f) ? 1 : 0;
    edat[slot] = make_int2((s << 8) | flag, __float_as_int(w));
}

// ---------------------------------------------------------------------------
// Degrees + dinv + norm-fold: pass 1 sums |w| by sign; pass 2 rewrites
// edat.y = w * (flag ? dinvn[t] : dinvp[t])  (same norm serves both layers).
// ---------------------------------------------------------------------------
__global__ void deg_dinv_kernel(const int* __restrict__ rowstart8,
                                int2* __restrict__ edat,
                                float* __restrict__ dinvp, float* __restrict__ dinvn, int n) {
    int t = blockIdx.x * blockDim.x + threadIdx.x;
    if (t >= n) return;
    int beg = rowstart8[8 * t], end = rowstart8[8 * t + 8];
    float p = 0.f, q = 0.f;
    for (int e = beg; e < end; ++e) {
        float w = __int_as_float(edat[e].y);
        p += fmaxf(w, 0.f);
        q += fmaxf(-w, 0.f);
    }
    float dp = rsqrtf(p + 1.0f), dn = rsqrtf(q + 1.0f);
    dinvp[t] = dp;
    dinvn[t] = dn;
    for (int e = beg; e < end; ++e) {
        int2 d = edat[e];
        float nv = __int_as_float(d.y) * ((d.x & 1) ? dn : dp);
        edat[e].y = __float_as_int(nv);
    }
}

// ---------------------------------------------------------------------------
// Tiled dual GEMM, fp32 compute, FP16 OUTPUT with dinv-scaled epilogue:
// hp' = half((X@Wp^T)*dinvp[row]).
// ---------------------------------------------------------------------------
template<int IN, int OUTF, bool DUAL>
__global__ __launch_bounds__(256) void gemm_tiled(
        const float* __restrict__ x,
        const float* __restrict__ Wp, const float* __restrict__ Wn,
        const float* __restrict__ dinvp, const float* __restrict__ dinvn,
        __half* __restrict__ hp, __half* __restrict__ hn, int n) {
    constexpr int BM = 64, BN = 128, BK = 32;
    __shared__ float xT[BK][BM + 4];
    __shared__ float Ws[BK][BN + 4];

    const int tid = threadIdx.x;
    const int rowbase = blockIdx.x * BM;
    const float* __restrict__ Wsel = DUAL ? nullptr : (blockIdx.y ? Wn : Wp);

    const int r0 = (tid & 15) * 4;
    const int c0 = (tid >> 4) * 8;

    float acc[4][8];
#pragma unroll
    for (int i = 0; i < 4; ++i)
#pragma unroll
        for (int j = 0; j < 8; ++j) acc[i][j] = 0.f;

    for (int k0 = 0; k0 < IN; k0 += BK) {
#pragma unroll
        for (int i = 0; i < (BM * BK) / (4 * TPB); ++i) {
            int lin = tid + i * TPB;
            int row = lin >> 3;
            int kq  = lin & 7;
            int grow = rowbase + row;
            if (grow > n - 1) grow = n - 1;
            float4 v = *(const float4*)(x + (size_t)grow * IN + k0 + kq * 4);
            int kk = kq * 4;
            xT[kk + 0][row] = v.x; xT[kk + 1][row] = v.y;
            xT[kk + 2][row] = v.z; xT[kk + 3][row] = v.w;
        }
#pragma unroll
        for (int i = 0; i < (BN * BK) / (4 * TPB); ++i) {
            int lin = tid + i * TPB;
            int c  = lin >> 3;
            int kq = lin & 7;
            const float* wrow;
            if (DUAL) wrow = (c < OUTF) ? (Wp + (size_t)c * IN) : (Wn + (size_t)(c - OUTF) * IN);
            else      wrow = Wsel + (size_t)c * IN;
            float4 v = *(const float4*)(wrow + k0 + kq * 4);
            int kk = kq * 4;
            Ws[kk + 0][c] = v.x; Ws[kk + 1][c] = v.y;
            Ws[kk + 2][c] = v.z; Ws[kk + 3][c] = v.w;
        }
        __syncthreads();

#pragma unroll
        for (int k = 0; k < BK; ++k) {
            float4 a  = *(const float4*)&xT[k][r0];
            float4 b0 = *(const float4*)&Ws[k][c0];
            float4 b1 = *(const float4*)&Ws[k][c0 + 4];
            const float av[4] = {a.x, a.y, a.z, a.w};
            const float bv[8] = {b0.x, b0.y, b0.z, b0.w, b1.x, b1.y, b1.z, b1.w};
#pragma unroll
            for (int i = 0; i < 4; ++i)
#pragma unroll
                for (int j = 0; j < 8; ++j) acc[i][j] += av[i] * bv[j];
        }
        __syncthreads();
    }

#pragma unroll
    for (int i = 0; i < 4; ++i) {
        int grow = rowbase + r0 + i;
        if (grow >= n) continue;
        __half* dst;
        float sc;
        if (DUAL) {
            bool isP = (c0 < OUTF);
            dst = isP ? (hp + (size_t)grow * OUTF + c0)
                      : (hn + (size_t)grow * OUTF + (c0 - OUTF));
            sc = isP ? dinvp[grow] : dinvn[grow];
        } else {
            dst = (blockIdx.y ? hn : hp) + (size_t)grow * OUTF + c0;
            sc = blockIdx.y ? dinvn[grow] : dinvp[grow];
        }
        union { __half2 h2[4]; uint4 u; } pk;
        pk.h2[0] = __floats2half2_rn(acc[i][0] * sc, acc[i][1] * sc);
        pk.h2[1] = __floats2half2_rn(acc[i][2] * sc, acc[i][3] * sc);
        pk.h2[2] = __floats2half2_rn(acc[i][4] * sc, acc[i][5] * sc);
        pk.h2[3] = __floats2half2_rn(acc[i][6] * sc, acc[i][7] * sc);
        *(uint4*)dst = pk.u;
    }
}

// ---------------------------------------------------------------------------
// Gather, F=128: one wave per target, wave-uniform scalar edge stream
// (readfirstlane -> s_load), norm pre-folded in edat.y, byte offset in
// edat.x, unroll x4 for MLP.
// ---------------------------------------------------------------------------
__global__ __launch_bounds__(256) void gather128_kernel(
        const int* __restrict__ rowstart8, const int2* __restrict__ edat,
        const __half* __restrict__ hp, const __half* __restrict__ hn,
        const float* __restrict__ dinvp, const float* __restrict__ dinvn,
        const float* __restrict__ bp, const float* __restrict__ bn,
        float* __restrict__ out, int n) {
    const int lane = threadIdx.x & 63;
    int t = (blockIdx.x * blockDim.x + threadIdx.x) >> 6;
    if (t >= n) return;
    t = __builtin_amdgcn_readfirstlane(t);
    const char* hpB = (const char*)hp;
    const char* hnB = (const char*)hn;
    int beg = rowstart8[8 * t], end = rowstart8[8 * t + 8];
    float2 acc0 = {0.f, 0.f}, acc1 = {0.f, 0.f};
    float2 acc2 = {0.f, 0.f}, acc3 = {0.f, 0.f};
    int e = beg;
    for (; e + 3 < end; e += 4) {
        int2 d0 = edat[e], d1 = edat[e + 1], d2 = edat[e + 2], d3 = edat[e + 3];
        const __half2* r0 = (const __half2*)(((d0.x & 1) ? hnB : hpB) + (d0.x & 0xFFFFFF00u));
        const __half2* r1 = (const __half2*)(((d1.x & 1) ? hnB : hpB) + (d1.x & 0xFFFFFF00u));
        const __half2* r2 = (const __half2*)(((d2.x & 1) ? hnB : hpB) + (d2.x & 0xFFFFFF00u));
        const __half2* r3 = (const __half2*)(((d3.x & 1) ? hnB : hpB) + (d3.x & 0xFFFFFF00u));
        float2 v0 = __half22float2(r0[lane]);
        float2 v1 = __half22float2(r1[lane]);
        float2 v2 = __half22float2(r2[lane]);
        float2 v3 = __half22float2(r3[lane]);
        float nv0 = __int_as_float(d0.y), nv1 = __int_as_float(d1.y);
        float nv2 = __int_as_float(d2.y), nv3 = __int_as_float(d3.y);
        acc0.x += v0.x * nv0; acc0.y += v0.y * nv0;
        acc1.x += v1.x * nv1; acc1.y += v1.y * nv1;
        acc2.x += v2.x * nv2; acc2.y += v2.y * nv2;
        acc3.x += v3.x * nv3; acc3.y += v3.y * nv3;
    }
    for (; e < end; ++e) {
        int2 d0 = edat[e];
        const __half2* r0 = (const __half2*)(((d0.x & 1) ? hnB : hpB) + (d0.x & 0xFFFFFF00u));
        float2 v0 = __half22float2(r0[lane]);
        float nv0 = __int_as_float(d0.y);
        acc0.x += v0.x * nv0; acc0.y += v0.y * nv0;
    }
    const float dp = dinvp[t], dn = dinvn[t];
    const __half2* hp2 = (const __half2*)hp;
    const __half2* hn2 = (const __half2*)hn;
    float2 hpv = __half22float2(hp2[(size_t)t * 64 + lane]);
    float2 hnv = __half22float2(hn2[(size_t)t * 64 + lane]);
    float o0 = acc0.x + acc1.x + acc2.x + acc3.x + hpv.x * dp + bp[2*lane]   - hnv.x * dn - bn[2*lane];
    float o1 = acc0.y + acc1.y + acc2.y + acc3.y + hpv.y * dp + bp[2*lane+1] - hnv.y * dn - bn[2*lane+1];
    float2 r = make_float2(fmaxf(o0, 0.f), fmaxf(o1, 0.f));
    *(float2*)(out + ((size_t)t << 7) + 2 * lane) = r;
}

// Gather, F=64 (fp16 rows are 128 B: offset = (edat.x & ~255) >> 1).
__global__ __launch_bounds__(256) void gather64_kernel(
        const int* __restrict__ rowstart8, const int2* __restrict__ edat,
        const __half* __restrict__ hp, const __half* __restrict__ hn,
        const float* __restrict__ dinvp, const float* __restrict__ dinvn,
        const float* __restrict__ bp, const float* __restrict__ bn,
        float* __restrict__ out, int n) {
    const int lane = threadIdx.x & 63;
    int t = (blockIdx.x * blockDim.x + threadIdx.x) >> 6;
    if (t >= n) return;
    t = __builtin_amdgcn_readfirstlane(t);
    const char* hpB = (const char*)hp;
    const char* hnB = (const char*)hn;
    int beg = rowstart8[8 * t], end = rowstart8[8 * t + 8];
    float acc0 = 0.f, acc1 = 0.f, acc2 = 0.f, acc3 = 0.f;
    int e = beg;
    for (; e + 3 < end; e += 4) {
        int2 d0 = edat[e], d1 = edat[e + 1], d2 = edat[e + 2], d3 = edat[e + 3];
        const __half* r0 = (const __half*)(((d0.x & 1) ? hnB : hpB) + ((d0.x & 0xFFFFFF00u) >> 1));
        const __half* r1 = (const __half*)(((d1.x & 1) ? hnB : hpB) + ((d1.x & 0xFFFFFF00u) >> 1));
        const __half* r2 = (const __half*)(((d2.x & 1) ? hnB : hpB) + ((d2.x & 0xFFFFFF00u) >> 1));
        const __half* r3 = (const __half*)(((d3.x & 1) ? hnB : hpB) + ((d3.x & 0xFFFFFF00u) >> 1));
        float v0 = __half2float(r0[lane]);
        float v1 = __half2float(r1[lane]);
        float v2 = __half2float(r2[lane]);
        float v3 = __half2float(r3[lane]);
        acc0 += v0 * __int_as_float(d0.y);
        acc1 += v1 * __int_as_float(d1.y);
        acc2 += v2 * __int_as_float(d2.y);
        acc3 += v3 * __int_as_float(d3.y);
    }
    for (; e < end; ++e) {
        int2 d0 = edat[e];
        const __half* r0 = (const __half*)(((d0.x & 1) ? hnB : hpB) + ((d0.x & 0xFFFFFF00u) >> 1));
        acc0 += __half2float(r0[lane]) * __int_as_float(d0.y);
    }
    const float dp = dinvp[t], dn = dinvn[t];
    float hpv = __half2float(hp[(size_t)t * 64 + lane]);
    float hnv = __half2float(hn[(size_t)t * 64 + lane]);
    float o = acc0 + acc1 + acc2 + acc3 + hpv * dp + bp[lane] - hnv * dn - bn[lane];
    out[(size_t)t * 64 + lane] = fmaxf(o, 0.f);
}

// ---------------------------------------------------------------------------
extern "C" void kernel_launch(void* const* d_in, const int* in_sizes, int n_in,
                              void* d_out, int out_size, void* d_ws, size_t ws_size,
                              hipStream_t stream) {
    const float* x   = (const float*)d_in[0];
    const int*   ei  = (const int*)d_in[1];
    const float* ew  = (const float*)d_in[2];
    const float* W1p = (const float*)d_in[3];
    const float* b1p = (const float*)d_in[4];
    const float* W1n = (const float*)d_in[5];
    const float* b1n = (const float*)d_in[6];
    const float* W2p = (const float*)d_in[7];
    const float* b2p = (const float*)d_in[8];
    const float* W2n = (const float*)d_in[9];
    const float* b2n = (const float*)d_in[10];

    const int E = in_sizes[2];
    const int n = in_sizes[0] / 64;  // IN = 64
    const int m = REPL * n;          // scan length
    const int* src = ei;
    const int* tgt = ei + E;

    // ws: dinvp[n]f | dinvn[n]f | blocksum[256]i | hp1[128n]h | hn1[128n]h | h[128n]f
    // layer2: hp2/hn2 (64n halves) reuse hp1; out2 (64n floats) reuses hn1.
    float*  ws    = (float*)d_ws;
    float*  dinvp = ws;
    float*  dinvn = ws + n;
    int*    blocksum = (int*)(ws + 2 * (size_t)n);
    __half* hp1   = (__half*)(ws + 2 * (size_t)n + 256);
    __half* hn1   = hp1 + (size_t)n * 128;
    float*  h     = (float*)(hn1 + (size_t)n * 128);
    __half* hp2   = hp1;
    __half* hn2   = hp1 + (size_t)n * 64;
    float*  out2  = (float*)hn1;

    // d_out ints: cntR[8n] | cursorR[8n] | rowstart8[8n+2] | edat[2E]
    int*  cntR      = (int*)d_out;
    int*  cursorR   = cntR + m;
    int*  rowstart8 = cntR + 2 * m;
    int2* edat      = (int2*)(cntR + 3 * m + 2);

    hipMemsetAsync(cntR, 0, 2 * (size_t)m * sizeof(int), stream);

    const int gridE = (E + TPB - 1) / TPB;
    const int gridN = (n + TPB - 1) / TPB;
    const int gridW = (n * 64 + TPB - 1) / TPB;
    const int gridM = (n + 63) / 64;
    const int gridS = (m + SCHUNK - 1) / SCHUNK;

    hist_kernel<<<gridE, TPB, 0, stream>>>(tgt, cntR, n, E);
    scan_reduce_kernel<<<gridS, TPB, 0, stream>>>(cntR, blocksum, n, m);
    scan_final_kernel<<<gridS, TPB, 0, stream>>>(cntR, blocksum, rowstart8, n, m);
    fill_kernel<<<gridE, TPB, 0, stream>>>(src, tgt, ew, rowstart8, cursorR, edat, n, E);
    deg_dinv_kernel<<<gridN, TPB, 0, stream>>>(rowstart8, edat, dinvp, dinvn, n);

    // ---- layer 1: IN=64 -> H=128 ----
    gemm_tiled<64, 128, false><<<dim3(gridM, 2), TPB, 0, stream>>>(
        x, W1p, W1n, dinvp, dinvn, hp1, hn1, n);
    gather128_kernel<<<gridW, TPB, 0, stream>>>(rowstart8, edat, hp1, hn1, dinvp, dinvn,
                                                b1p, b1n, h, n);

    // ---- layer 2: H=128 -> OUT=64 (both matrices in one BN=128 pass) ----
    gemm_tiled<128, 64, true><<<dim3(gridM, 1), TPB, 0, stream>>>(
        h, W2p, W2n, dinvp, dinvn, hp2, hn2, n);
    gather64_kernel<<<gridW, TPB, 0, stream>>>(rowstart8, edat, hp2, hn2, dinvp, dinvn,
                                               b2p, b2n, out2, n);

    hipMemcpyAsync(d_out, out2, (size_t)n * 64 * sizeof(float),
                   hipMemcpyDeviceToDevice, stream);
}